// Round 1
// baseline (2540.554 us; speedup 1.0000x reference)
//
#include <hip/hip_runtime.h>
#include <cstdint>
#include <cstddef>

// Model dims (fixed by the problem)
#define BB    2
#define TSEQ  512
#define EDIM  768
#define NHEAD 12
#define HDIM  64
#define VDIM  256
#define PDIM  4
#define NROW  (BB*TSEQ)        // 1024
#define NROW2 (BB*TSEQ*PDIM)   // 4096

__device__ __forceinline__ float gelu_f(float v){
    return 0.5f * v * (1.0f + erff(v * 0.70710678118654752f));
}

// ---------------------------------------------------------------------------
// Generic fp32 GEMM: C = op(A[M,K] @ W[K,N] (+bias)) (+resid)
// BM=BN=64, BK=16, 256 threads, 4x4 micro-tile per thread.
// All M,N,K here are multiples of 64/64/16.
// ---------------------------------------------------------------------------
template<int ACT, int RESID>
__global__ __launch_bounds__(256) void gemm64(
    const float* __restrict__ A, const float* __restrict__ W,
    const float* __restrict__ bias, const float* __restrict__ resid,
    float* __restrict__ C, int M, int N, int K)
{
    __shared__ float As[16][64];
    __shared__ float Ws[16][64];
    const int tid = threadIdx.x;
    const int bm = blockIdx.y * 64, bn = blockIdx.x * 64;
    const int tx = tid & 15, ty = tid >> 4;
    const int arow = tid >> 2, akq = tid & 3;
    const int wkk = tid >> 4, wnq = tid & 15;
    float acc[4][4] = {};
    for(int k0 = 0; k0 < K; k0 += 16){
        float4 av = *(const float4*)(A + (size_t)(bm + arow) * K + k0 + akq * 4);
        float4 wv = *(const float4*)(W + (size_t)(k0 + wkk) * N + bn + wnq * 4);
        As[akq*4+0][arow] = av.x;
        As[akq*4+1][arow] = av.y;
        As[akq*4+2][arow] = av.z;
        As[akq*4+3][arow] = av.w;
        *(float4*)(&Ws[wkk][wnq*4]) = wv;
        __syncthreads();
        #pragma unroll
        for(int kk = 0; kk < 16; kk++){
            float a0 = As[kk][ty*4+0];
            float a1 = As[kk][ty*4+1];
            float a2 = As[kk][ty*4+2];
            float a3 = As[kk][ty*4+3];
            float4 bv = *(const float4*)(&Ws[kk][tx*4]);
            acc[0][0] += a0*bv.x; acc[0][1] += a0*bv.y; acc[0][2] += a0*bv.z; acc[0][3] += a0*bv.w;
            acc[1][0] += a1*bv.x; acc[1][1] += a1*bv.y; acc[1][2] += a1*bv.z; acc[1][3] += a1*bv.w;
            acc[2][0] += a2*bv.x; acc[2][1] += a2*bv.y; acc[2][2] += a2*bv.z; acc[2][3] += a2*bv.w;
            acc[3][0] += a3*bv.x; acc[3][1] += a3*bv.y; acc[3][2] += a3*bv.z; acc[3][3] += a3*bv.w;
        }
        __syncthreads();
    }
    #pragma unroll
    for(int i = 0; i < 4; i++){
        int r  = bm + ty*4 + i;
        int c0 = bn + tx*4;
        float4 v = make_float4(acc[i][0], acc[i][1], acc[i][2], acc[i][3]);
        if(bias){
            v.x += bias[c0+0]; v.y += bias[c0+1]; v.z += bias[c0+2]; v.w += bias[c0+3];
        }
        if(ACT == 1){
            v.x = gelu_f(v.x); v.y = gelu_f(v.y); v.z = gelu_f(v.z); v.w = gelu_f(v.w);
        }
        if(RESID){
            float4 rv = *(const float4*)(resid + (size_t)r*N + c0);
            v.x += rv.x; v.y += rv.y; v.z += rv.z; v.w += rv.w;
        }
        *(float4*)(C + (size_t)r*N + c0) = v;
    }
}

// ---------------------------------------------------------------------------
// LayerNorm over last dim D (256 threads per row). out = (x[+x2]-m)*rstd*g+b
// ---------------------------------------------------------------------------
__global__ __launch_bounds__(256) void ln_kernel(
    const float* __restrict__ in, const float* __restrict__ in2,
    const float* __restrict__ g, const float* __restrict__ bta,
    float* __restrict__ out, int D)
{
    const int row = blockIdx.x;
    const float* xr  = in + (size_t)row * D;
    const float* x2r = in2 ? in2 + (size_t)row * D : nullptr;
    const int tid = threadIdx.x;
    const int nper = D / 256;          // 3 (E=768) or 1 (V=256)
    float vals[3];
    float sum = 0.f, sq = 0.f;
    for(int i = 0; i < nper; i++){
        int d = tid + i*256;
        float v = xr[d];
        if(x2r) v += x2r[d];
        vals[i] = v; sum += v; sq += v*v;
    }
    #pragma unroll
    for(int off = 32; off > 0; off >>= 1){
        sum += __shfl_xor(sum, off, 64);
        sq  += __shfl_xor(sq,  off, 64);
    }
    __shared__ float ssum[4], ssq[4];
    __shared__ float smean, srstd;
    int wid = tid >> 6;
    if((tid & 63) == 0){ ssum[wid] = sum; ssq[wid] = sq; }
    __syncthreads();
    if(tid == 0){
        float S = 0.f, Q = 0.f;
        for(int w = 0; w < 4; w++){ S += ssum[w]; Q += ssq[w]; }
        float m = S / D;
        float var = Q / D - m*m;
        smean = m;
        srstd = rsqrtf(fmaxf(var, 0.f) + 1e-5f);
    }
    __syncthreads();
    float m = smean, r = srstd;
    for(int i = 0; i < nper; i++){
        int d = tid + i*256;
        out[(size_t)row*D + d] = (vals[i] - m) * r * g[d] + bta[d];
    }
}

// ---------------------------------------------------------------------------
// Embedding gather: x0 = x = emb[tokens]
// ---------------------------------------------------------------------------
__global__ __launch_bounds__(192) void embed_kernel(
    const int* __restrict__ tokens, const float* __restrict__ emb,
    float* __restrict__ x0, float* __restrict__ x)
{
    const int row = blockIdx.x;
    const int tok = tokens[row];
    const float4* src = (const float4*)(emb + (size_t)tok * EDIM);
    float4* d0 = (float4*)(x0 + (size_t)row * EDIM);
    float4* d1 = (float4*)(x  + (size_t)row * EDIM);
    for(int i = threadIdx.x; i < EDIM/4; i += blockDim.x){
        float4 v = src[i]; d0[i] = v; d1[i] = v;
    }
}

// ---------------------------------------------------------------------------
// RoPE tables for T positions, HD/2=32 dims.
// ---------------------------------------------------------------------------
__global__ __launch_bounds__(256) void rope_kernel(float* __restrict__ rc, float* __restrict__ rs)
{
    int i = blockIdx.x * 256 + threadIdx.x;   // 512*32 = 16384
    int pos = i >> 5, d = i & 31;
    float inv = powf(10000.0f, -(float)(2*d) / 64.0f);
    float f = (float)pos * inv;
    rc[i] = cosf(f);
    rs[i] = sinf(f);
}

// ---------------------------------------------------------------------------
// Sliding-window causal attention, window S, RoPE fused, residual add into x.
// One block per (t, h, b); 128 threads (thread j = key slot, thread d = out dim).
// ---------------------------------------------------------------------------
__global__ __launch_bounds__(128) void patch_attn(
    const float* __restrict__ qkv, const float* __restrict__ rc,
    const float* __restrict__ rs, float* __restrict__ x, int S)
{
    const int t = blockIdx.x, h = blockIdx.y, b = blockIdx.z;
    const int tid = threadIdx.x;
    __shared__ float qs[64];
    __shared__ float pbuf[128];
    __shared__ float red[128];
    const float* qrow = qkv + (size_t)(b*TSEQ + t) * (3*EDIM) + h*HDIM;
    if(tid < 64){
        int d = tid, dp = d & 31;
        float c = rc[t*32 + dp], s = rs[t*32 + dp];
        float x1 = qrow[dp], x2 = qrow[dp + 32];
        qs[d] = (d < 32) ? (x1*c - x2*s) : (x1*s + x2*c);
    }
    __syncthreads();
    const int j = tid;
    const int pos = t - S + 1 + j;
    float score = -1e30f;
    if(j < S && pos >= 0){
        const float* krow = qkv + (size_t)(b*TSEQ + pos) * (3*EDIM) + EDIM + h*HDIM;
        float acc = 0.f;
        for(int dp = 0; dp < 32; dp++){
            float c = rc[pos*32 + dp], s = rs[pos*32 + dp];
            float k1 = krow[dp], k2 = krow[dp + 32];
            acc += qs[dp]      * (k1*c - k2*s)
                 + qs[dp + 32] * (k1*s + k2*c);
        }
        score = acc * 0.125f;   // HD^-0.5
    }
    red[tid] = score;
    __syncthreads();
    #pragma unroll
    for(int off = 64; off > 0; off >>= 1){
        if(tid < off) red[tid] = fmaxf(red[tid], red[tid + off]);
        __syncthreads();
    }
    float m = red[0];
    __syncthreads();
    float pv = (j < S && pos >= 0) ? expf(score - m) : 0.f;
    pbuf[tid] = pv;
    red[tid] = pv;
    __syncthreads();
    #pragma unroll
    for(int off = 64; off > 0; off >>= 1){
        if(tid < off) red[tid] += red[tid + off];
        __syncthreads();
    }
    float inv_den = 1.f / red[0];
    if(tid < 64){
        int d = tid;
        float o = 0.f;
        int jstart = (t - S + 1 < 0) ? (S - 1 - t) : 0;
        for(int jj = jstart; jj < S; jj++){
            int pp = t - S + 1 + jj;
            o += pbuf[jj] * qkv[(size_t)(b*TSEQ + pp) * (3*EDIM) + 2*EDIM + h*HDIM + d];
        }
        x[(size_t)(b*TSEQ + t) * EDIM + h*HDIM + d] += o * inv_den;
    }
}

// ---------------------------------------------------------------------------
// P-axis attention (4 positions, full softmax, RoPE). Block = 4 waves,
// wave p = query position p, lane = head dim d. One block per (t,h,b).
// ---------------------------------------------------------------------------
__global__ __launch_bounds__(256) void sa_attn(
    const float* __restrict__ qkv2, float* __restrict__ o)
{
    const int t = blockIdx.x, h = blockIdx.y, b = blockIdx.z;
    const int p = threadIdx.x >> 6, lane = threadIdx.x & 63;
    const int row0 = (b*TSEQ + t) * PDIM;
    const float* base = qkv2 + (size_t)row0 * (3*EDIM);
    const int d = lane, dp = d & 31;
    const float inv = powf(10000.0f, -(float)(2*dp) / 64.0f);
    // RoPE'd query (position p)
    float q1 = base[(size_t)p*(3*EDIM) + h*HDIM + dp];
    float q2 = base[(size_t)p*(3*EDIM) + h*HDIM + dp + 32];
    float cp = cosf(p * inv), sp = sinf(p * inv);
    float qr = (d < 32) ? (q1*cp - q2*sp) : (q1*sp + q2*cp);
    float sc[4];
    #pragma unroll
    for(int j = 0; j < 4; j++){
        float k1 = base[(size_t)j*(3*EDIM) + EDIM + h*HDIM + dp];
        float k2 = base[(size_t)j*(3*EDIM) + EDIM + h*HDIM + dp + 32];
        float cj = cosf(j * inv), sj = sinf(j * inv);
        float kr = (d < 32) ? (k1*cj - k2*sj) : (k1*sj + k2*cj);
        float v = qr * kr;
        #pragma unroll
        for(int off = 32; off > 0; off >>= 1) v += __shfl_xor(v, off, 64);
        sc[j] = v * 0.125f;
    }
    float m = fmaxf(fmaxf(sc[0], sc[1]), fmaxf(sc[2], sc[3]));
    float e0 = expf(sc[0]-m), e1 = expf(sc[1]-m), e2 = expf(sc[2]-m), e3 = expf(sc[3]-m);
    float idn = 1.f / (e0 + e1 + e2 + e3);
    float ov = (e0 * base[0*(3*EDIM) + 2*EDIM + h*HDIM + d]
              + e1 * base[1*(3*EDIM) + 2*EDIM + h*HDIM + d]
              + e2 * base[2*(3*EDIM) + 2*EDIM + h*HDIM + d]
              + e3 * base[3*(3*EDIM) + 2*EDIM + h*HDIM + d]) * idn;
    o[(size_t)(row0 + p) * EDIM + h*HDIM + d] = ov;
}

// ---------------------------------------------------------------------------
// out[b,t,:] = x2[(b,t,p=0),:]
// ---------------------------------------------------------------------------
__global__ __launch_bounds__(256) void outcopy(const float* __restrict__ x2, float* __restrict__ out)
{
    int i = blockIdx.x * 256 + threadIdx.x;    // B*T*V = 262144
    int row = i >> 8, col = i & 255;
    out[i] = x2[(size_t)row * PDIM * VDIM + col];
}

// ---------------------------------------------------------------------------
extern "C" void kernel_launch(void* const* d_in, const int* in_sizes, int n_in,
                              void* d_out, int out_size, void* d_ws, size_t ws_size,
                              hipStream_t stream)
{
    const int*   tokens    = (const int*)  d_in[0];
    const float* emb       = (const float*)d_in[1];
    const float* bl0g      = (const float*)d_in[2];
    const float* bl0b      = (const float*)d_in[3];
    const float* bl1g      = (const float*)d_in[4];
    const float* bl1b      = (const float*)d_in[5];
    const float* qkv_w     = (const float*)d_in[6];
    const float* ff_w1     = (const float*)d_in[7];
    const float* ff_b1     = (const float*)d_in[8];
    const float* ff_w2     = (const float*)d_in[9];
    const float* ff_b2     = (const float*)d_in[10];
    const float* fin_g     = (const float*)d_in[11];
    const float* fin_b     = (const float*)d_in[12];
    const float* head_w    = (const float*)d_in[13];
    const float* head_b    = (const float*)d_in[14];
    const float* sa_ln0_g  = (const float*)d_in[15];
    const float* sa_ln0_b  = (const float*)d_in[16];
    const float* sa_ln1_g  = (const float*)d_in[17];
    const float* sa_ln1_b  = (const float*)d_in[18];
    const float* sa_qkv_w  = (const float*)d_in[19];
    const float* sa_proj_w = (const float*)d_in[20];
    const float* sa_proj_b = (const float*)d_in[21];
    const float* sa_ff_w1  = (const float*)d_in[22];
    const float* sa_ff_b1  = (const float*)d_in[23];
    const float* sa_ff_w2  = (const float*)d_in[24];
    const float* sa_ff_b2  = (const float*)d_in[25];
    float* out = (float*)d_out;

    // Workspace layout (float offsets). Phase-1 and phase-2 buffers alias.
    float* ws     = (float*)d_ws;
    float* logits = ws;                        // 4096*256   = 1,048,576
    float* U      = ws + 1048576;
    // phase 1
    float* x0    = U;                          //  786,432
    float* x     = U + 786432;                 //  786,432
    float* h     = U + 1572864;                //  786,432
    float* qkv   = U + 2359296;                // 2,359,296
    float* ff1   = U + 4718592;                // 3,145,728
    float* ropec = U + 7864320;                //   16,384
    float* ropes = U + 7880704;                //   16,384
    // phase 2 (aliases phase-1 region, which is dead by then)
    float* qkv2   = U;                         // 9,437,184
    float* sa_o   = U + 9437184;               // 3,145,728
    float* sa_ff1 = U + 12582912;              // 4,194,304
    float* h2     = U + 16777216;              // 1,048,576
    // total: 18,874,368 floats = 72 MiB

    // ---- embed + rope tables ----
    embed_kernel<<<NROW, 192, 0, stream>>>(tokens, emb, x0, x);
    rope_kernel<<<64, 256, 0, stream>>>(ropec, ropes);

    // ---- 4 main layers ----
    for(int i = 0; i < 4; i++){
        const int S = 16 << i;
        ln_kernel<<<NROW, 256, 0, stream>>>(x, nullptr, bl0g + i*EDIM, bl0b + i*EDIM, h, EDIM);
        gemm64<0,0><<<dim3(3*EDIM/64, NROW/64), 256, 0, stream>>>(
            h, qkv_w + (size_t)i*EDIM*3*EDIM, nullptr, nullptr, qkv, NROW, 3*EDIM, EDIM);
        patch_attn<<<dim3(TSEQ, NHEAD, BB), 128, 0, stream>>>(qkv, ropec, ropes, x, S);
        ln_kernel<<<NROW, 256, 0, stream>>>(x, nullptr, bl1g + i*EDIM, bl1b + i*EDIM, h, EDIM);
        gemm64<1,0><<<dim3(4*EDIM/64, NROW/64), 256, 0, stream>>>(
            h, ff_w1 + (size_t)i*EDIM*4*EDIM, ff_b1 + (size_t)i*4*EDIM, nullptr, ff1, NROW, 4*EDIM, EDIM);
        gemm64<0,1><<<dim3(EDIM/64, NROW/64), 256, 0, stream>>>(
            ff1, ff_w2 + (size_t)i*4*EDIM*EDIM, ff_b2 + (size_t)i*EDIM, x, x, NROW, EDIM, 4*EDIM);
    }

    // ---- final LN(x0 + x) + head ----
    ln_kernel<<<NROW, 256, 0, stream>>>(x, x0, fin_g, fin_b, h, EDIM);
    gemm64<0,0><<<dim3(PDIM*VDIM/64, NROW/64), 256, 0, stream>>>(
        h, head_w, head_b, nullptr, logits, NROW, PDIM*VDIM, EDIM);

    // ---- sa block over (B*T*P, V) ----
    ln_kernel<<<NROW2, 256, 0, stream>>>(logits, nullptr, sa_ln0_g, sa_ln0_b, h2, VDIM);
    gemm64<0,0><<<dim3(3*EDIM/64, NROW2/64), 256, 0, stream>>>(
        h2, sa_qkv_w, nullptr, nullptr, qkv2, NROW2, 3*EDIM, VDIM);
    sa_attn<<<dim3(TSEQ, NHEAD, BB), 256, 0, stream>>>(qkv2, sa_o);
    gemm64<0,1><<<dim3(VDIM/64, NROW2/64), 256, 0, stream>>>(
        sa_o, sa_proj_w, sa_proj_b, logits, logits, NROW2, VDIM, EDIM);
    ln_kernel<<<NROW2, 256, 0, stream>>>(logits, nullptr, sa_ln1_g, sa_ln1_b, h2, VDIM);
    gemm64<1,0><<<dim3(4*VDIM/64, NROW2/64), 256, 0, stream>>>(
        h2, sa_ff_w1, sa_ff_b1, nullptr, sa_ff1, NROW2, 4*VDIM, VDIM);
    gemm64<0,1><<<dim3(VDIM/64, NROW2/64), 256, 0, stream>>>(
        sa_ff1, sa_ff_w2, sa_ff_b2, logits, logits, NROW2, VDIM, 4*VDIM);

    // ---- output: p = 0 slice ----
    outcopy<<<(out_size + 255)/256, 256, 0, stream>>>(logits, out);
}

// Round 2
// 1069.889 us; speedup vs baseline: 2.3746x; 2.3746x over previous
//
#include <hip/hip_runtime.h>
#include <hip/hip_bf16.h>
#include <cstdint>
#include <cstddef>

// Model dims (fixed by the problem)
#define BB    2
#define TSEQ  512
#define EDIM  768
#define NHEAD 12
#define HDIM  64
#define VDIM  256
#define PDIM  4
#define NROW  (BB*TSEQ)        // 1024
#define NROW2 (BB*TSEQ*PDIM)   // 4096

typedef __attribute__((ext_vector_type(8))) short short8;
typedef __attribute__((ext_vector_type(4))) float floatx4;

__device__ __forceinline__ float gelu_f(float v){
    return 0.5f * v * (1.0f + erff(v * 0.70710678118654752f));
}

__device__ __forceinline__ void gload16(const void* g, void* l){
    __builtin_amdgcn_global_load_lds((const __attribute__((address_space(1))) void*)g,
                                     (__attribute__((address_space(3))) void*)l, 16, 0, 0);
}

// ---------------------------------------------------------------------------
// Weight convert+transpose: in fp32 [K,N] row-major -> out bf16 [N,K] row-major.
// 32x32 tiles via LDS (padded), coalesced read + coalesced bf16 write.
// ---------------------------------------------------------------------------
__global__ __launch_bounds__(256) void wconv(
    const float* __restrict__ in, __hip_bfloat16* __restrict__ out, int K, int N)
{
    __shared__ float t[32][33];
    const int n0 = blockIdx.x * 32, k0 = blockIdx.y * 32;
    const int c = threadIdx.x & 31, r0 = threadIdx.x >> 5;   // 8 row-groups
    #pragma unroll
    for(int r = r0; r < 32; r += 8)
        t[r][c] = in[(size_t)(k0 + r) * N + n0 + c];
    __syncthreads();
    #pragma unroll
    for(int r = r0; r < 32; r += 8)
        out[(size_t)(n0 + r) * K + k0 + c] = __float2bfloat16(t[c][r]);
}

// ---------------------------------------------------------------------------
// MFMA GEMM (m97 structure): C = op(A[M,K] @ Bt[N,K]^T (+bias)) (+resid)
// A, Bt bf16; acc fp32. 128x128 tile, BK=32, 256 threads = 4 waves (2x2 of 64x64).
// M%128==0, N%128==0, K%32==0.
// ---------------------------------------------------------------------------
template<int ACT, int RESID, int OUTBF16>
__global__ __launch_bounds__(256) void gemm128(
    const short* __restrict__ A, const short* __restrict__ Bt,
    const float* __restrict__ bias, const float* __restrict__ resid,
    void* __restrict__ Cout, int M, int N, int K)
{
    __shared__ short As[128*32];
    __shared__ short Bs[128*32];
    const int tid  = threadIdx.x;
    const int lane = tid & 63;
    const int wave = tid >> 6;
    const int bm = blockIdx.y * 128, bn = blockIdx.x * 128;
    const int wm = (wave >> 1) * 64, wn = (wave & 1) * 64;
    const int quad = lane >> 4, l16 = lane & 15;

    floatx4 acc[4][4];
    #pragma unroll
    for(int i = 0; i < 4; i++)
        #pragma unroll
        for(int j = 0; j < 4; j++)
            acc[i][j] = floatx4{0.f, 0.f, 0.f, 0.f};

    const int r  = tid >> 2;           // 0..63 (issue 1 adds 64)
    const int c8 = (tid & 3) * 8;
    const int ldsoff = (tid & 192) * 16;   // wave-uniform byte base within issue

    for(int k0 = 0; k0 < K; k0 += 32){
        gload16(A  + (size_t)(bm + r     ) * K + k0 + c8, (char*)As + ldsoff);
        gload16(A  + (size_t)(bm + r + 64) * K + k0 + c8, (char*)As + 4096 + ldsoff);
        gload16(Bt + (size_t)(bn + r     ) * K + k0 + c8, (char*)Bs + ldsoff);
        gload16(Bt + (size_t)(bn + r + 64) * K + k0 + c8, (char*)Bs + 4096 + ldsoff);
        __syncthreads();
        short8 af[4], bfr[4];
        #pragma unroll
        for(int i = 0; i < 4; i++){
            af[i]  = *(const short8*)&As[(wm + i*16 + l16)*32 + quad*8];
            bfr[i] = *(const short8*)&Bs[(wn + i*16 + l16)*32 + quad*8];
        }
        #pragma unroll
        for(int i = 0; i < 4; i++)
            #pragma unroll
            for(int j = 0; j < 4; j++)
                acc[i][j] = __builtin_amdgcn_mfma_f32_16x16x32_bf16(af[i], bfr[j], acc[i][j], 0, 0, 0);
        __syncthreads();
    }

    float* Cf = (float*)Cout;
    __hip_bfloat16* Cb = (__hip_bfloat16*)Cout;
    #pragma unroll
    for(int i = 0; i < 4; i++){
        int row0 = bm + wm + i*16 + quad*4;
        #pragma unroll
        for(int j = 0; j < 4; j++){
            int col = bn + wn + j*16 + l16;
            float bv = bias ? bias[col] : 0.f;
            #pragma unroll
            for(int rr = 0; rr < 4; rr++){
                float v = acc[i][j][rr] + bv;
                if(ACT) v = gelu_f(v);
                if(RESID) v += resid[(size_t)(row0 + rr) * N + col];
                if(OUTBF16) Cb[(size_t)(row0 + rr) * N + col] = __float2bfloat16(v);
                else        Cf[(size_t)(row0 + rr) * N + col] = v;
            }
        }
    }
}

// ---------------------------------------------------------------------------
// 64x64-tile variant for small-N GEMMs (more blocks -> better CU coverage).
// 4 waves in 2x2 of 32x32. M%64==0, N%64==0, K%32==0.
// ---------------------------------------------------------------------------
template<int ACT, int RESID, int OUTBF16>
__global__ __launch_bounds__(256) void gemm64t(
    const short* __restrict__ A, const short* __restrict__ Bt,
    const float* __restrict__ bias, const float* __restrict__ resid,
    void* __restrict__ Cout, int M, int N, int K)
{
    __shared__ short As[64*32];
    __shared__ short Bs[64*32];
    const int tid  = threadIdx.x;
    const int lane = tid & 63;
    const int wave = tid >> 6;
    const int bm = blockIdx.y * 64, bn = blockIdx.x * 64;
    const int wm = (wave >> 1) * 32, wn = (wave & 1) * 32;
    const int quad = lane >> 4, l16 = lane & 15;

    floatx4 acc[2][2];
    #pragma unroll
    for(int i = 0; i < 2; i++)
        #pragma unroll
        for(int j = 0; j < 2; j++)
            acc[i][j] = floatx4{0.f, 0.f, 0.f, 0.f};

    const int r  = tid >> 2;
    const int c8 = (tid & 3) * 8;
    const int ldsoff = (tid & 192) * 16;

    for(int k0 = 0; k0 < K; k0 += 32){
        gload16(A  + (size_t)(bm + r) * K + k0 + c8, (char*)As + ldsoff);
        gload16(Bt + (size_t)(bn + r) * K + k0 + c8, (char*)Bs + ldsoff);
        __syncthreads();
        short8 af[2], bfr[2];
        #pragma unroll
        for(int i = 0; i < 2; i++){
            af[i]  = *(const short8*)&As[(wm + i*16 + l16)*32 + quad*8];
            bfr[i] = *(const short8*)&Bs[(wn + i*16 + l16)*32 + quad*8];
        }
        #pragma unroll
        for(int i = 0; i < 2; i++)
            #pragma unroll
            for(int j = 0; j < 2; j++)
                acc[i][j] = __builtin_amdgcn_mfma_f32_16x16x32_bf16(af[i], bfr[j], acc[i][j], 0, 0, 0);
        __syncthreads();
    }

    float* Cf = (float*)Cout;
    __hip_bfloat16* Cb = (__hip_bfloat16*)Cout;
    #pragma unroll
    for(int i = 0; i < 2; i++){
        int row0 = bm + wm + i*16 + quad*4;
        #pragma unroll
        for(int j = 0; j < 2; j++){
            int col = bn + wn + j*16 + l16;
            float bv = bias ? bias[col] : 0.f;
            #pragma unroll
            for(int rr = 0; rr < 4; rr++){
                float v = acc[i][j][rr] + bv;
                if(ACT) v = gelu_f(v);
                if(RESID) v += resid[(size_t)(row0 + rr) * N + col];
                if(OUTBF16) Cb[(size_t)(row0 + rr) * N + col] = __float2bfloat16(v);
                else        Cf[(size_t)(row0 + rr) * N + col] = v;
            }
        }
    }
}

// ---------------------------------------------------------------------------
// LayerNorm over last dim D (256 threads per row). out = (x[+x2]-m)*rstd*g+b
// fp32 in, bf16 out.
// ---------------------------------------------------------------------------
__global__ __launch_bounds__(256) void ln_kernel(
    const float* __restrict__ in, const float* __restrict__ in2,
    const float* __restrict__ g, const float* __restrict__ bta,
    __hip_bfloat16* __restrict__ out, int D)
{
    const int row = blockIdx.x;
    const float* xr  = in + (size_t)row * D;
    const float* x2r = in2 ? in2 + (size_t)row * D : nullptr;
    const int tid = threadIdx.x;
    const int nper = D / 256;          // 3 (E=768) or 1 (V=256)
    float vals[3];
    float sum = 0.f, sq = 0.f;
    for(int i = 0; i < nper; i++){
        int d = tid + i*256;
        float v = xr[d];
        if(x2r) v += x2r[d];
        vals[i] = v; sum += v; sq += v*v;
    }
    #pragma unroll
    for(int off = 32; off > 0; off >>= 1){
        sum += __shfl_xor(sum, off, 64);
        sq  += __shfl_xor(sq,  off, 64);
    }
    __shared__ float ssum[4], ssq[4];
    __shared__ float smean, srstd;
    int wid = tid >> 6;
    if((tid & 63) == 0){ ssum[wid] = sum; ssq[wid] = sq; }
    __syncthreads();
    if(tid == 0){
        float S = 0.f, Q = 0.f;
        for(int w = 0; w < 4; w++){ S += ssum[w]; Q += ssq[w]; }
        float m = S / D;
        float var = Q / D - m*m;
        smean = m;
        srstd = rsqrtf(fmaxf(var, 0.f) + 1e-5f);
    }
    __syncthreads();
    float m = smean, rs = srstd;
    for(int i = 0; i < nper; i++){
        int d = tid + i*256;
        out[(size_t)row*D + d] = __float2bfloat16((vals[i] - m) * rs * g[d] + bta[d]);
    }
}

// ---------------------------------------------------------------------------
__global__ __launch_bounds__(192) void embed_kernel(
    const int* __restrict__ tokens, const float* __restrict__ emb,
    float* __restrict__ x0, float* __restrict__ x)
{
    const int row = blockIdx.x;
    const int tok = tokens[row];
    const float4* src = (const float4*)(emb + (size_t)tok * EDIM);
    float4* d0 = (float4*)(x0 + (size_t)row * EDIM);
    float4* d1 = (float4*)(x  + (size_t)row * EDIM);
    for(int i = threadIdx.x; i < EDIM/4; i += blockDim.x){
        float4 v = src[i]; d0[i] = v; d1[i] = v;
    }
}

// ---------------------------------------------------------------------------
__global__ __launch_bounds__(256) void rope_kernel(float* __restrict__ rc, float* __restrict__ rs)
{
    int i = blockIdx.x * 256 + threadIdx.x;   // 512*32 = 16384
    int pos = i >> 5, d = i & 31;
    float inv = powf(10000.0f, -(float)(2*d) / 64.0f);
    float f = (float)pos * inv;
    rc[i] = cosf(f);
    rs[i] = sinf(f);
}

// ---------------------------------------------------------------------------
// Sliding-window causal attention over bf16 qkv, residual add into fp32 x.
// ---------------------------------------------------------------------------
__global__ __launch_bounds__(128) void patch_attn(
    const __hip_bfloat16* __restrict__ qkv, const float* __restrict__ rc,
    const float* __restrict__ rs, float* __restrict__ x, int S)
{
    const int t = blockIdx.x, h = blockIdx.y, b = blockIdx.z;
    const int tid = threadIdx.x;
    __shared__ float qs[64];
    __shared__ float pbuf[128];
    __shared__ float red[128];
    const __hip_bfloat16* qrow = qkv + (size_t)(b*TSEQ + t) * (3*EDIM) + h*HDIM;
    if(tid < 64){
        int d = tid, dp = d & 31;
        float c = rc[t*32 + dp], s = rs[t*32 + dp];
        float x1 = __bfloat162float(qrow[dp]), x2 = __bfloat162float(qrow[dp + 32]);
        qs[d] = (d < 32) ? (x1*c - x2*s) : (x1*s + x2*c);
    }
    __syncthreads();
    const int j = tid;
    const int pos = t - S + 1 + j;
    float score = -1e30f;
    if(j < S && pos >= 0){
        const __hip_bfloat16* krow = qkv + (size_t)(b*TSEQ + pos) * (3*EDIM) + EDIM + h*HDIM;
        float acc = 0.f;
        for(int dp = 0; dp < 32; dp++){
            float c = rc[pos*32 + dp], s = rs[pos*32 + dp];
            float k1 = __bfloat162float(krow[dp]), k2 = __bfloat162float(krow[dp + 32]);
            acc += qs[dp]      * (k1*c - k2*s)
                 + qs[dp + 32] * (k1*s + k2*c);
        }
        score = acc * 0.125f;   // HD^-0.5
    }
    red[tid] = score;
    __syncthreads();
    #pragma unroll
    for(int off = 64; off > 0; off >>= 1){
        if(tid < off) red[tid] = fmaxf(red[tid], red[tid + off]);
        __syncthreads();
    }
    float m = red[0];
    __syncthreads();
    float pv = (j < S && pos >= 0) ? expf(score - m) : 0.f;
    pbuf[tid] = pv;
    red[tid] = pv;
    __syncthreads();
    #pragma unroll
    for(int off = 64; off > 0; off >>= 1){
        if(tid < off) red[tid] += red[tid + off];
        __syncthreads();
    }
    float inv_den = 1.f / red[0];
    if(tid < 64){
        int d = tid;
        float o = 0.f;
        int jstart = (t - S + 1 < 0) ? (S - 1 - t) : 0;
        for(int jj = jstart; jj < S; jj++){
            int pp = t - S + 1 + jj;
            o += pbuf[jj] * __bfloat162float(qkv[(size_t)(b*TSEQ + pp) * (3*EDIM) + 2*EDIM + h*HDIM + d]);
        }
        x[(size_t)(b*TSEQ + t) * EDIM + h*HDIM + d] += o * inv_den;
    }
}

// ---------------------------------------------------------------------------
// P-axis attention (4 positions, full softmax, RoPE), bf16 in/out.
// ---------------------------------------------------------------------------
__global__ __launch_bounds__(256) void sa_attn(
    const __hip_bfloat16* __restrict__ qkv2, __hip_bfloat16* __restrict__ o)
{
    const int t = blockIdx.x, h = blockIdx.y, b = blockIdx.z;
    const int p = threadIdx.x >> 6, lane = threadIdx.x & 63;
    const int row0 = (b*TSEQ + t) * PDIM;
    const __hip_bfloat16* base = qkv2 + (size_t)row0 * (3*EDIM);
    const int d = lane, dp = d & 31;
    const float inv = powf(10000.0f, -(float)(2*dp) / 64.0f);
    float q1 = __bfloat162float(base[(size_t)p*(3*EDIM) + h*HDIM + dp]);
    float q2 = __bfloat162float(base[(size_t)p*(3*EDIM) + h*HDIM + dp + 32]);
    float cp = cosf(p * inv), sp = sinf(p * inv);
    float qr = (d < 32) ? (q1*cp - q2*sp) : (q1*sp + q2*cp);
    float sc[4];
    #pragma unroll
    for(int j = 0; j < 4; j++){
        float k1 = __bfloat162float(base[(size_t)j*(3*EDIM) + EDIM + h*HDIM + dp]);
        float k2 = __bfloat162float(base[(size_t)j*(3*EDIM) + EDIM + h*HDIM + dp + 32]);
        float cj = cosf(j * inv), sj = sinf(j * inv);
        float kr = (d < 32) ? (k1*cj - k2*sj) : (k1*sj + k2*cj);
        float v = qr * kr;
        #pragma unroll
        for(int off = 32; off > 0; off >>= 1) v += __shfl_xor(v, off, 64);
        sc[j] = v * 0.125f;
    }
    float m = fmaxf(fmaxf(sc[0], sc[1]), fmaxf(sc[2], sc[3]));
    float e0 = expf(sc[0]-m), e1 = expf(sc[1]-m), e2 = expf(sc[2]-m), e3 = expf(sc[3]-m);
    float idn = 1.f / (e0 + e1 + e2 + e3);
    float ov = (e0 * __bfloat162float(base[0*(3*EDIM) + 2*EDIM + h*HDIM + d])
              + e1 * __bfloat162float(base[1*(3*EDIM) + 2*EDIM + h*HDIM + d])
              + e2 * __bfloat162float(base[2*(3*EDIM) + 2*EDIM + h*HDIM + d])
              + e3 * __bfloat162float(base[3*(3*EDIM) + 2*EDIM + h*HDIM + d])) * idn;
    o[(size_t)(row0 + p) * EDIM + h*HDIM + d] = __float2bfloat16(ov);
}

// ---------------------------------------------------------------------------
__global__ __launch_bounds__(256) void outcopy(const float* __restrict__ x2, float* __restrict__ out)
{
    int i = blockIdx.x * 256 + threadIdx.x;    // B*T*V = 262144
    int row = i >> 8, col = i & 255;
    out[i] = x2[(size_t)row * PDIM * VDIM + col];
}

// ---------------------------------------------------------------------------
extern "C" void kernel_launch(void* const* d_in, const int* in_sizes, int n_in,
                              void* d_out, int out_size, void* d_ws, size_t ws_size,
                              hipStream_t stream)
{
    const int*   tokens    = (const int*)  d_in[0];
    const float* emb       = (const float*)d_in[1];
    const float* bl0g      = (const float*)d_in[2];
    const float* bl0b      = (const float*)d_in[3];
    const float* bl1g      = (const float*)d_in[4];
    const float* bl1b      = (const float*)d_in[5];
    const float* qkv_w     = (const float*)d_in[6];
    const float* ff_w1     = (const float*)d_in[7];
    const float* ff_b1     = (const float*)d_in[8];
    const float* ff_w2     = (const float*)d_in[9];
    const float* ff_b2     = (const float*)d_in[10];
    const float* fin_g     = (const float*)d_in[11];
    const float* fin_b     = (const float*)d_in[12];
    const float* head_w    = (const float*)d_in[13];
    const float* head_b    = (const float*)d_in[14];
    const float* sa_ln0_g  = (const float*)d_in[15];
    const float* sa_ln0_b  = (const float*)d_in[16];
    const float* sa_ln1_g  = (const float*)d_in[17];
    const float* sa_ln1_b  = (const float*)d_in[18];
    const float* sa_qkv_w  = (const float*)d_in[19];
    const float* sa_proj_w = (const float*)d_in[20];
    const float* sa_proj_b = (const float*)d_in[21];
    const float* sa_ff_w1  = (const float*)d_in[22];
    const float* sa_ff_b1  = (const float*)d_in[23];
    const float* sa_ff_w2  = (const float*)d_in[24];
    const float* sa_ff_b2  = (const float*)d_in[25];
    float* out = (float*)d_out;

    // ---- workspace layout (byte offsets) ----
    char* base = (char*)d_ws;
    float* logits           = (float*)(base);                    // 4,194,304
    float* ropec            = (float*)(base + 4194304);          //    65,536
    float* ropes            = (float*)(base + 4259840);          //    65,536
    __hip_bfloat16* wqkvT   = (__hip_bfloat16*)(base + 4325376); // 3,538,944 (per-layer, reused)
    __hip_bfloat16* wff1T   = (__hip_bfloat16*)(base + 7864320); // 4,718,592
    __hip_bfloat16* wff2T   = (__hip_bfloat16*)(base + 12582912);// 4,718,592
    __hip_bfloat16* wheadT  = (__hip_bfloat16*)(base + 17301504);// 1,572,864
    __hip_bfloat16* wsaqkvT = (__hip_bfloat16*)(base + 18874368);// 1,179,648
    __hip_bfloat16* wsaprojT= (__hip_bfloat16*)(base + 20054016);//   393,216
    __hip_bfloat16* wsaff1T = (__hip_bfloat16*)(base + 20447232);//   524,288
    __hip_bfloat16* wsaff2T = (__hip_bfloat16*)(base + 20971520);//   524,288
    char* U = base + 21495808;
    // phase 1
    float* x0           = (float*)(U);                           // 3,145,728
    float* x            = (float*)(U + 3145728);                 // 3,145,728
    __hip_bfloat16* h   = (__hip_bfloat16*)(U + 6291456);        // 1,572,864
    __hip_bfloat16* qkv = (__hip_bfloat16*)(U + 7864320);        // 4,718,592
    __hip_bfloat16* ff1 = (__hip_bfloat16*)(U + 12582912);       // 6,291,456
    // phase 2 (aliases phase 1, dead by then)
    __hip_bfloat16* h2    = (__hip_bfloat16*)(U);                // 2,097,152
    __hip_bfloat16* qkv2  = (__hip_bfloat16*)(U + 2097152);      // 18,874,368
    __hip_bfloat16* sa_o  = (__hip_bfloat16*)(U + 20971520);     // 6,291,456
    __hip_bfloat16* sa_f1 = (__hip_bfloat16*)(U + 27262976);     // 8,388,608
    // total = 21,495,808 + 35,651,584 = 57,147,392 B (< 72 MiB proven available)

    // ---- embed + rope + one-time weight conversions ----
    embed_kernel<<<NROW, 192, 0, stream>>>(tokens, emb, x0, x);
    rope_kernel<<<64, 256, 0, stream>>>(ropec, ropes);
    wconv<<<dim3(1024/32, 768/32), 256, 0, stream>>>(head_w,    wheadT,  768,  1024);
    wconv<<<dim3(2304/32, 256/32), 256, 0, stream>>>(sa_qkv_w,  wsaqkvT, 256,  2304);
    wconv<<<dim3( 256/32, 768/32), 256, 0, stream>>>(sa_proj_w, wsaprojT,768,  256);
    wconv<<<dim3(1024/32, 256/32), 256, 0, stream>>>(sa_ff_w1,  wsaff1T, 256,  1024);
    wconv<<<dim3( 256/32,1024/32), 256, 0, stream>>>(sa_ff_w2,  wsaff2T, 1024, 256);

    // ---- 4 main layers ----
    for(int i = 0; i < 4; i++){
        const int S = 16 << i;
        wconv<<<dim3(2304/32, 768/32), 256, 0, stream>>>(qkv_w + (size_t)i*EDIM*3*EDIM, wqkvT, 768, 2304);
        wconv<<<dim3(3072/32, 768/32), 256, 0, stream>>>(ff_w1 + (size_t)i*EDIM*4*EDIM, wff1T, 768, 3072);
        wconv<<<dim3( 768/32,3072/32), 256, 0, stream>>>(ff_w2 + (size_t)i*4*EDIM*EDIM, wff2T, 3072, 768);

        ln_kernel<<<NROW, 256, 0, stream>>>(x, nullptr, bl0g + i*EDIM, bl0b + i*EDIM, h, EDIM);
        gemm128<0,0,1><<<dim3(18, 8), 256, 0, stream>>>(
            (const short*)h, (const short*)wqkvT, nullptr, nullptr, qkv, NROW, 3*EDIM, EDIM);
        patch_attn<<<dim3(TSEQ, NHEAD, BB), 128, 0, stream>>>(qkv, ropec, ropes, x, S);
        ln_kernel<<<NROW, 256, 0, stream>>>(x, nullptr, bl1g + i*EDIM, bl1b + i*EDIM, h, EDIM);
        gemm128<1,0,1><<<dim3(24, 8), 256, 0, stream>>>(
            (const short*)h, (const short*)wff1T, ff_b1 + (size_t)i*4*EDIM, nullptr, ff1, NROW, 4*EDIM, EDIM);
        gemm64t<0,1,0><<<dim3(12, 16), 256, 0, stream>>>(
            (const short*)ff1, (const short*)wff2T, ff_b2 + (size_t)i*EDIM, x, x, NROW, EDIM, 4*EDIM);
    }

    // ---- final LN(x0 + x) + head ----
    ln_kernel<<<NROW, 256, 0, stream>>>(x, x0, fin_g, fin_b, h, EDIM);
    gemm64t<0,0,0><<<dim3(16, 16), 256, 0, stream>>>(
        (const short*)h, (const short*)wheadT, head_b, nullptr, logits, NROW, PDIM*VDIM, EDIM);

    // ---- sa block over (B*T*P, V) ----
    ln_kernel<<<NROW2, 256, 0, stream>>>(logits, nullptr, sa_ln0_g, sa_ln0_b, h2, VDIM);
    gemm128<0,0,1><<<dim3(18, 32), 256, 0, stream>>>(
        (const short*)h2, (const short*)wsaqkvT, nullptr, nullptr, qkv2, NROW2, 3*EDIM, VDIM);
    sa_attn<<<dim3(TSEQ, NHEAD, BB), 256, 0, stream>>>(qkv2, sa_o);
    gemm64t<0,1,0><<<dim3(4, 64), 256, 0, stream>>>(
        (const short*)sa_o, (const short*)wsaprojT, sa_proj_b, logits, logits, NROW2, VDIM, EDIM);
    ln_kernel<<<NROW2, 256, 0, stream>>>(logits, nullptr, sa_ln1_g, sa_ln1_b, h2, VDIM);
    gemm128<1,0,1><<<dim3(8, 32), 256, 0, stream>>>(
        (const short*)h2, (const short*)wsaff1T, sa_ff_b1, nullptr, sa_f1, NROW2, 4*VDIM, VDIM);
    gemm64t<0,1,0><<<dim3(4, 64), 256, 0, stream>>>(
        (const short*)sa_f1, (const short*)wsaff2T, sa_ff_b2, logits, logits, NROW2, VDIM, 4*VDIM);

    // ---- output: p = 0 slice ----
    outcopy<<<(out_size + 255)/256, 256, 0, stream>>>(logits, out);
}

// Round 4
// 852.419 us; speedup vs baseline: 2.9804x; 1.2551x over previous
//
#include <hip/hip_runtime.h>
#include <hip/hip_bf16.h>
#include <cstdint>
#include <cstddef>

// Model dims (fixed by the problem)
#define BB    2
#define TSEQ  512
#define EDIM  768
#define NHEAD 12
#define HDIM  64
#define VDIM  256
#define PDIM  4
#define NROW  (BB*TSEQ)        // 1024
#define NROW2 (BB*TSEQ*PDIM)   // 4096

typedef __attribute__((ext_vector_type(8))) short short8;
typedef __attribute__((ext_vector_type(4))) float floatx4;

__device__ __forceinline__ float gelu_f(float v){
    return 0.5f * v * (1.0f + erff(v * 0.70710678118654752f));
}

__device__ __forceinline__ float b2f(short s){
    unsigned u = ((unsigned)(unsigned short)s) << 16;
    float f; __builtin_memcpy(&f, &u, 4); return f;
}

__device__ __forceinline__ void gload16(const void* g, void* l){
    __builtin_amdgcn_global_load_lds((const __attribute__((address_space(1))) void*)g,
                                     (__attribute__((address_space(3))) void*)l, 16, 0, 0);
}

// ---------------------------------------------------------------------------
// Weight convert+transpose: in fp32 [K,N] row-major -> out bf16 [N,K] row-major.
// ---------------------------------------------------------------------------
__global__ __launch_bounds__(256) void wconv(
    const float* __restrict__ in, __hip_bfloat16* __restrict__ out, int K, int N)
{
    __shared__ float t[32][33];
    const int n0 = blockIdx.x * 32, k0 = blockIdx.y * 32;
    const int c = threadIdx.x & 31, r0 = threadIdx.x >> 5;   // 8 row-groups
    #pragma unroll
    for(int r = r0; r < 32; r += 8)
        t[r][c] = in[(size_t)(k0 + r) * N + n0 + c];
    __syncthreads();
    #pragma unroll
    for(int r = r0; r < 32; r += 8)
        out[(size_t)(n0 + r) * K + k0 + c] = __float2bfloat16(t[c][r]);
}

// ---------------------------------------------------------------------------
// MFMA GEMM (m97 structure): C = op(A[M,K] @ Bt[N,K]^T (+bias)) (+resid)
// 128x128 tile, BK=32, 256 threads = 4 waves (2x2 of 64x64).
// ---------------------------------------------------------------------------
template<int ACT, int RESID, int OUTBF16>
__global__ __launch_bounds__(256) void gemm128(
    const short* __restrict__ A, const short* __restrict__ Bt,
    const float* __restrict__ bias, const float* __restrict__ resid,
    void* __restrict__ Cout, int M, int N, int K)
{
    alignas(16) __shared__ short As[128*32];
    alignas(16) __shared__ short Bs[128*32];
    const int tid  = threadIdx.x;
    const int lane = tid & 63;
    const int wave = tid >> 6;
    const int bm = blockIdx.y * 128, bn = blockIdx.x * 128;
    const int wm = (wave >> 1) * 64, wn = (wave & 1) * 64;
    const int quad = lane >> 4, l16 = lane & 15;

    floatx4 acc[4][4];
    #pragma unroll
    for(int i = 0; i < 4; i++)
        #pragma unroll
        for(int j = 0; j < 4; j++)
            acc[i][j] = floatx4{0.f, 0.f, 0.f, 0.f};

    const int r  = tid >> 2;
    const int c8 = (tid & 3) * 8;
    const int ldsoff = (tid & 192) * 16;

    for(int k0 = 0; k0 < K; k0 += 32){
        gload16(A  + (size_t)(bm + r     ) * K + k0 + c8, (char*)As + ldsoff);
        gload16(A  + (size_t)(bm + r + 64) * K + k0 + c8, (char*)As + 4096 + ldsoff);
        gload16(Bt + (size_t)(bn + r     ) * K + k0 + c8, (char*)Bs + ldsoff);
        gload16(Bt + (size_t)(bn + r + 64) * K + k0 + c8, (char*)Bs + 4096 + ldsoff);
        __syncthreads();
        short8 af[4], bfr[4];
        #pragma unroll
        for(int i = 0; i < 4; i++){
            af[i]  = *(const short8*)&As[(wm + i*16 + l16)*32 + quad*8];
            bfr[i] = *(const short8*)&Bs[(wn + i*16 + l16)*32 + quad*8];
        }
        #pragma unroll
        for(int i = 0; i < 4; i++)
            #pragma unroll
            for(int j = 0; j < 4; j++)
                acc[i][j] = __builtin_amdgcn_mfma_f32_16x16x32_bf16(af[i], bfr[j], acc[i][j], 0, 0, 0);
        __syncthreads();
    }

    float* Cf = (float*)Cout;
    __hip_bfloat16* Cb = (__hip_bfloat16*)Cout;
    #pragma unroll
    for(int i = 0; i < 4; i++){
        int row0 = bm + wm + i*16 + quad*4;
        #pragma unroll
        for(int j = 0; j < 4; j++){
            int col = bn + wn + j*16 + l16;
            float bv = bias ? bias[col] : 0.f;
            #pragma unroll
            for(int rr = 0; rr < 4; rr++){
                float v = acc[i][j][rr] + bv;
                if(ACT) v = gelu_f(v);
                if(RESID) v += resid[(size_t)(row0 + rr) * N + col];
                if(OUTBF16) Cb[(size_t)(row0 + rr) * N + col] = __float2bfloat16(v);
                else        Cf[(size_t)(row0 + rr) * N + col] = v;
            }
        }
    }
}

// ---------------------------------------------------------------------------
// 64x64-tile variant for small-N GEMMs.
// ---------------------------------------------------------------------------
template<int ACT, int RESID, int OUTBF16>
__global__ __launch_bounds__(256) void gemm64t(
    const short* __restrict__ A, const short* __restrict__ Bt,
    const float* __restrict__ bias, const float* __restrict__ resid,
    void* __restrict__ Cout, int M, int N, int K)
{
    alignas(16) __shared__ short As[64*32];
    alignas(16) __shared__ short Bs[64*32];
    const int tid  = threadIdx.x;
    const int lane = tid & 63;
    const int wave = tid >> 6;
    const int bm = blockIdx.y * 64, bn = blockIdx.x * 64;
    const int wm = (wave >> 1) * 32, wn = (wave & 1) * 32;
    const int quad = lane >> 4, l16 = lane & 15;

    floatx4 acc[2][2];
    #pragma unroll
    for(int i = 0; i < 2; i++)
        #pragma unroll
        for(int j = 0; j < 2; j++)
            acc[i][j] = floatx4{0.f, 0.f, 0.f, 0.f};

    const int r  = tid >> 2;
    const int c8 = (tid & 3) * 8;
    const int ldsoff = (tid & 192) * 16;

    for(int k0 = 0; k0 < K; k0 += 32){
        gload16(A  + (size_t)(bm + r) * K + k0 + c8, (char*)As + ldsoff);
        gload16(Bt + (size_t)(bn + r) * K + k0 + c8, (char*)Bs + ldsoff);
        __syncthreads();
        short8 af[2], bfr[2];
        #pragma unroll
        for(int i = 0; i < 2; i++){
            af[i]  = *(const short8*)&As[(wm + i*16 + l16)*32 + quad*8];
            bfr[i] = *(const short8*)&Bs[(wn + i*16 + l16)*32 + quad*8];
        }
        #pragma unroll
        for(int i = 0; i < 2; i++)
            #pragma unroll
            for(int j = 0; j < 2; j++)
                acc[i][j] = __builtin_amdgcn_mfma_f32_16x16x32_bf16(af[i], bfr[j], acc[i][j], 0, 0, 0);
        __syncthreads();
    }

    float* Cf = (float*)Cout;
    __hip_bfloat16* Cb = (__hip_bfloat16*)Cout;
    #pragma unroll
    for(int i = 0; i < 2; i++){
        int row0 = bm + wm + i*16 + quad*4;
        #pragma unroll
        for(int j = 0; j < 2; j++){
            int col = bn + wn + j*16 + l16;
            float bv = bias ? bias[col] : 0.f;
            #pragma unroll
            for(int rr = 0; rr < 4; rr++){
                float v = acc[i][j][rr] + bv;
                if(ACT) v = gelu_f(v);
                if(RESID) v += resid[(size_t)(row0 + rr) * N + col];
                if(OUTBF16) Cb[(size_t)(row0 + rr) * N + col] = __float2bfloat16(v);
                else        Cf[(size_t)(row0 + rr) * N + col] = v;
            }
        }
    }
}

// ---------------------------------------------------------------------------
// LayerNorm over last dim D. fp32 in, bf16 out.
// ---------------------------------------------------------------------------
__global__ __launch_bounds__(256) void ln_kernel(
    const float* __restrict__ in, const float* __restrict__ in2,
    const float* __restrict__ g, const float* __restrict__ bta,
    __hip_bfloat16* __restrict__ out, int D)
{
    const int row = blockIdx.x;
    const float* xr  = in + (size_t)row * D;
    const float* x2r = in2 ? in2 + (size_t)row * D : nullptr;
    const int tid = threadIdx.x;
    const int nper = D / 256;
    float vals[3];
    float sum = 0.f, sq = 0.f;
    for(int i = 0; i < nper; i++){
        int d = tid + i*256;
        float v = xr[d];
        if(x2r) v += x2r[d];
        vals[i] = v; sum += v; sq += v*v;
    }
    #pragma unroll
    for(int off = 32; off > 0; off >>= 1){
        sum += __shfl_xor(sum, off, 64);
        sq  += __shfl_xor(sq,  off, 64);
    }
    __shared__ float ssum[4], ssq[4];
    __shared__ float smean, srstd;
    int wid = tid >> 6;
    if((tid & 63) == 0){ ssum[wid] = sum; ssq[wid] = sq; }
    __syncthreads();
    if(tid == 0){
        float S = 0.f, Q = 0.f;
        for(int w = 0; w < 4; w++){ S += ssum[w]; Q += ssq[w]; }
        float m = S / D;
        float var = Q / D - m*m;
        smean = m;
        srstd = rsqrtf(fmaxf(var, 0.f) + 1e-5f);
    }
    __syncthreads();
    float m = smean, rs = srstd;
    for(int i = 0; i < nper; i++){
        int d = tid + i*256;
        out[(size_t)row*D + d] = __float2bfloat16((vals[i] - m) * rs * g[d] + bta[d]);
    }
}

// ---------------------------------------------------------------------------
__global__ __launch_bounds__(192) void embed_kernel(
    const int* __restrict__ tokens, const float* __restrict__ emb,
    float* __restrict__ x0, float* __restrict__ x)
{
    const int row = blockIdx.x;
    const int tok = tokens[row];
    const float4* src = (const float4*)(emb + (size_t)tok * EDIM);
    float4* d0 = (float4*)(x0 + (size_t)row * EDIM);
    float4* d1 = (float4*)(x  + (size_t)row * EDIM);
    for(int i = threadIdx.x; i < EDIM/4; i += blockDim.x){
        float4 v = src[i]; d0[i] = v; d1[i] = v;
    }
}

// ---------------------------------------------------------------------------
__global__ __launch_bounds__(256) void rope_kernel(float* __restrict__ rc, float* __restrict__ rs)
{
    int i = blockIdx.x * 256 + threadIdx.x;   // 512*32 = 16384
    int pos = i >> 5, d = i & 31;
    float inv = powf(10000.0f, -(float)(2*d) / 64.0f);
    float f = (float)pos * inv;
    rc[i] = cosf(f);
    rs[i] = sinf(f);
}

// ---------------------------------------------------------------------------
// qkv [B*T, 2304] bf16 -> rotated q, rotated k, v in head-major [B,NH,T,64] bf16
// ---------------------------------------------------------------------------
__global__ __launch_bounds__(256) void rope_qkv(
    const __hip_bfloat16* __restrict__ qkv,
    const float* __restrict__ rc, const float* __restrict__ rs,
    __hip_bfloat16* __restrict__ qr, __hip_bfloat16* __restrict__ kr,
    __hip_bfloat16* __restrict__ vv)
{
    const int row = blockIdx.x;            // b*T + t
    const int b = row / TSEQ, t = row % TSEQ;
    const int lane = threadIdx.x & 63;
    const int hg = threadIdx.x >> 6;       // 0..3
    const int d = lane, dp = d & 31;
    const float cc = rc[t*32 + dp], ss = rs[t*32 + dp];
    #pragma unroll
    for(int it = 0; it < 3; it++){
        int h = it*4 + hg;
        const __hip_bfloat16* src = qkv + (size_t)row*(3*EDIM) + h*HDIM;
        float q1 = __bfloat162float(src[dp]),        q2 = __bfloat162float(src[dp+32]);
        float k1 = __bfloat162float(src[EDIM+dp]),   k2 = __bfloat162float(src[EDIM+dp+32]);
        float qv = (d < 32) ? (q1*cc - q2*ss) : (q1*ss + q2*cc);
        float kv = (d < 32) ? (k1*cc - k2*ss) : (k1*ss + k2*cc);
        size_t didx = ((size_t)(b*NHEAD + h)*TSEQ + t)*HDIM + d;
        qr[didx] = __float2bfloat16(qv);
        kr[didx] = __float2bfloat16(kv);
        vv[didx] = src[2*EDIM + d];
    }
}

// ---------------------------------------------------------------------------
// Sliding-window attention v2. 4 waves/block = 4 consecutive queries.
// K/V window staged in LDS with 16B XOR-swizzled chunks. Residual add into x.
// ---------------------------------------------------------------------------
template<int S>
__global__ __launch_bounds__(256) void patch_attn2(
    const __hip_bfloat16* __restrict__ qr, const __hip_bfloat16* __restrict__ kr,
    const __hip_bfloat16* __restrict__ vv, float* __restrict__ x)
{
    constexpr int W = S + 3;               // staged window rows
    alignas(16) __shared__ short Ks[W*64];
    alignas(16) __shared__ short Vs[W*64];
    __shared__ float qlds[4*64];
    __shared__ float pb[4*128];

    const int t0 = blockIdx.x * 4;
    const int h = blockIdx.y, b = blockIdx.z;
    const int tid = threadIdx.x;
    const int wv = tid >> 6, lane = tid & 63;
    const size_t headbase = ((size_t)(b*NHEAD + h)) * TSEQ;

    // ---- stage K,V window rows [t0-S+1 .. t0+3], swizzled chunks ----
    const int c = tid & 7;
    for(int r = tid >> 3; r < W; r += 32){
        int g = t0 - S + 1 + r;
        int gc = g < 0 ? 0 : g;            // clamped: masked later, stays finite
        int sc = (c ^ (r & 7)) * 8;
        *(short8*)&Ks[r*64 + sc] = *(const short8*)((const short*)kr + (headbase + gc)*64 + c*8);
        *(short8*)&Vs[r*64 + sc] = *(const short8*)((const short*)vv + (headbase + gc)*64 + c*8);
    }
    qlds[wv*64 + lane] = __bfloat162float(qr[(headbase + t0 + wv)*64 + lane]);
    __syncthreads();

    const int t = t0 + wv;
    // ---- scores: lane = key j (and j+64 for S=128) ----
    const int r0 = (S >= 64) ? (wv + lane) : ((lane < S) ? (wv + lane) : 0);
    const int r1 = wv + lane + 64;         // only used when S==128 (always < W)
    float a0 = 0.f, a1 = 0.f;
    #pragma unroll
    for(int ch = 0; ch < 8; ch++){
        float4 qa = *(const float4*)&qlds[wv*64 + ch*8];
        float4 qb = *(const float4*)&qlds[wv*64 + ch*8 + 4];
        short8 k0 = *(const short8*)&Ks[r0*64 + ((ch ^ (r0 & 7))*8)];
        a0 += qa.x*b2f(k0[0]) + qa.y*b2f(k0[1]) + qa.z*b2f(k0[2]) + qa.w*b2f(k0[3])
            + qb.x*b2f(k0[4]) + qb.y*b2f(k0[5]) + qb.z*b2f(k0[6]) + qb.w*b2f(k0[7]);
        if(S == 128){
            short8 k1 = *(const short8*)&Ks[r1*64 + ((ch ^ (r1 & 7))*8)];
            a1 += qa.x*b2f(k1[0]) + qa.y*b2f(k1[1]) + qa.z*b2f(k1[2]) + qa.w*b2f(k1[3])
                + qb.x*b2f(k1[4]) + qb.y*b2f(k1[5]) + qb.z*b2f(k1[6]) + qb.w*b2f(k1[7]);
        }
    }
    const int key0 = t - S + 1 + lane;
    const bool v0 = (lane < S) && (key0 >= 0);
    const bool v1 = (S == 128) && (key0 + 64 >= 0);
    float s0 = v0 ? a0 * 0.125f : -1e30f;
    float s1 = v1 ? a1 * 0.125f : -1e30f;
    float mx = fmaxf(s0, s1);
    #pragma unroll
    for(int off = 32; off > 0; off >>= 1) mx = fmaxf(mx, __shfl_xor(mx, off, 64));
    float p0 = v0 ? expf(s0 - mx) : 0.f;
    float p1 = v1 ? expf(s1 - mx) : 0.f;
    float sm = p0 + p1;
    #pragma unroll
    for(int off = 32; off > 0; off >>= 1) sm += __shfl_xor(sm, off, 64);
    const float inv = 1.f / sm;
    pb[wv*128 + lane] = p0 * inv;
    if(S == 128) pb[wv*128 + lane + 64] = p1 * inv;
    __syncthreads();

    // ---- PV: lane = d ----
    const int d = lane;
    const int coff = d >> 3, dlo = d & 7;
    float o = 0.f;
    #pragma unroll 8
    for(int j = 0; j < S; j++){
        int r = wv + j;
        float p = pb[wv*128 + j];
        o += p * b2f(Vs[r*64 + ((coff ^ (r & 7))*8) + dlo]);
    }
    x[((size_t)(b*TSEQ) + t) * EDIM + h*HDIM + d] += o;
}

// ---------------------------------------------------------------------------
// P-axis attention (4 positions, full softmax, RoPE), bf16 in/out.
// ---------------------------------------------------------------------------
__global__ __launch_bounds__(256) void sa_attn(
    const __hip_bfloat16* __restrict__ qkv2, __hip_bfloat16* __restrict__ o)
{
    const int t = blockIdx.x, h = blockIdx.y, b = blockIdx.z;
    const int p = threadIdx.x >> 6, lane = threadIdx.x & 63;
    const int row0 = (b*TSEQ + t) * PDIM;
    const __hip_bfloat16* base = qkv2 + (size_t)row0 * (3*EDIM);
    const int d = lane, dp = d & 31;
    const float inv = powf(10000.0f, -(float)(2*dp) / 64.0f);
    float q1 = __bfloat162float(base[(size_t)p*(3*EDIM) + h*HDIM + dp]);
    float q2 = __bfloat162float(base[(size_t)p*(3*EDIM) + h*HDIM + dp + 32]);
    float cp = cosf(p * inv), sp = sinf(p * inv);
    float qr = (d < 32) ? (q1*cp - q2*sp) : (q1*sp + q2*cp);
    float sc[4];
    #pragma unroll
    for(int j = 0; j < 4; j++){
        float k1 = __bfloat162float(base[(size_t)j*(3*EDIM) + EDIM + h*HDIM + dp]);
        float k2 = __bfloat162float(base[(size_t)j*(3*EDIM) + EDIM + h*HDIM + dp + 32]);
        float cj = cosf(j * inv), sj = sinf(j * inv);
        float kr = (d < 32) ? (k1*cj - k2*sj) : (k1*sj + k2*cj);
        float v = qr * kr;
        #pragma unroll
        for(int off = 32; off > 0; off >>= 1) v += __shfl_xor(v, off, 64);
        sc[j] = v * 0.125f;
    }
    float m = fmaxf(fmaxf(sc[0], sc[1]), fmaxf(sc[2], sc[3]));
    float e0 = expf(sc[0]-m), e1 = expf(sc[1]-m), e2 = expf(sc[2]-m), e3 = expf(sc[3]-m);
    float idn = 1.f / (e0 + e1 + e2 + e3);
    float ov = (e0 * __bfloat162float(base[0*(3*EDIM) + 2*EDIM + h*HDIM + d])
              + e1 * __bfloat162float(base[1*(3*EDIM) + 2*EDIM + h*HDIM + d])
              + e2 * __bfloat162float(base[2*(3*EDIM) + 2*EDIM + h*HDIM + d])
              + e3 * __bfloat162float(base[3*(3*EDIM) + 2*EDIM + h*HDIM + d])) * idn;
    o[(size_t)(row0 + p) * EDIM + h*HDIM + d] = __float2bfloat16(ov);
}

// ---------------------------------------------------------------------------
__global__ __launch_bounds__(256) void outcopy(const float* __restrict__ x2, float* __restrict__ out)
{
    int i = blockIdx.x * 256 + threadIdx.x;    // B*T*V = 262144
    int row = i >> 8, col = i & 255;
    out[i] = x2[(size_t)row * PDIM * VDIM + col];
}

// ---------------------------------------------------------------------------
extern "C" void kernel_launch(void* const* d_in, const int* in_sizes, int n_in,
                              void* d_out, int out_size, void* d_ws, size_t ws_size,
                              hipStream_t stream)
{
    const int*   tokens    = (const int*)  d_in[0];
    const float* emb       = (const float*)d_in[1];
    const float* bl0g      = (const float*)d_in[2];
    const float* bl0b      = (const float*)d_in[3];
    const float* bl1g      = (const float*)d_in[4];
    const float* bl1b      = (const float*)d_in[5];
    const float* qkv_w     = (const float*)d_in[6];
    const float* ff_w1     = (const float*)d_in[7];
    const float* ff_b1     = (const float*)d_in[8];
    const float* ff_w2     = (const float*)d_in[9];
    const float* ff_b2     = (const float*)d_in[10];
    const float* fin_g     = (const float*)d_in[11];
    const float* fin_b     = (const float*)d_in[12];
    const float* head_w    = (const float*)d_in[13];
    const float* head_b    = (const float*)d_in[14];
    const float* sa_ln0_g  = (const float*)d_in[15];
    const float* sa_ln0_b  = (const float*)d_in[16];
    const float* sa_ln1_g  = (const float*)d_in[17];
    const float* sa_ln1_b  = (const float*)d_in[18];
    const float* sa_qkv_w  = (const float*)d_in[19];
    const float* sa_proj_w = (const float*)d_in[20];
    const float* sa_proj_b = (const float*)d_in[21];
    const float* sa_ff_w1  = (const float*)d_in[22];
    const float* sa_ff_b1  = (const float*)d_in[23];
    const float* sa_ff_w2  = (const float*)d_in[24];
    const float* sa_ff_b2  = (const float*)d_in[25];
    float* out = (float*)d_out;

    // ---- workspace layout (byte offsets) ----
    char* base = (char*)d_ws;
    float* logits           = (float*)(base);                    // 4,194,304
    float* ropec            = (float*)(base + 4194304);          //    65,536
    float* ropes            = (float*)(base + 4259840);          //    65,536
    __hip_bfloat16* wqkvT   = (__hip_bfloat16*)(base + 4325376); // 3,538,944 (per-layer, reused)
    __hip_bfloat16* wff1T   = (__hip_bfloat16*)(base + 7864320); // 4,718,592
    __hip_bfloat16* wff2T   = (__hip_bfloat16*)(base + 12582912);// 4,718,592
    __hip_bfloat16* wheadT  = (__hip_bfloat16*)(base + 17301504);// 1,572,864
    __hip_bfloat16* wsaqkvT = (__hip_bfloat16*)(base + 18874368);// 1,179,648
    __hip_bfloat16* wsaprojT= (__hip_bfloat16*)(base + 20054016);//   393,216
    __hip_bfloat16* wsaff1T = (__hip_bfloat16*)(base + 20447232);//   524,288
    __hip_bfloat16* wsaff2T = (__hip_bfloat16*)(base + 20971520);//   524,288
    char* U = base + 21495808;
    // phase 1
    float* x0           = (float*)(U);                           // 3,145,728
    float* x            = (float*)(U + 3145728);                 // 3,145,728
    __hip_bfloat16* h   = (__hip_bfloat16*)(U + 6291456);        // 1,572,864
    __hip_bfloat16* qkv = (__hip_bfloat16*)(U + 7864320);        // 4,718,592
    __hip_bfloat16* ff1 = (__hip_bfloat16*)(U + 12582912);       // 6,291,456
    __hip_bfloat16* qrb = (__hip_bfloat16*)(U + 18874368);       // 1,572,864
    __hip_bfloat16* krb = (__hip_bfloat16*)(U + 20447232);       // 1,572,864
    __hip_bfloat16* vvb = (__hip_bfloat16*)(U + 22020096);       // 1,572,864
    // phase 2 (aliases phase 1, dead by then)
    __hip_bfloat16* h2    = (__hip_bfloat16*)(U);                // 2,097,152
    __hip_bfloat16* qkv2  = (__hip_bfloat16*)(U + 2097152);      // 18,874,368
    __hip_bfloat16* sa_o  = (__hip_bfloat16*)(U + 20971520);     // 6,291,456
    __hip_bfloat16* sa_f1 = (__hip_bfloat16*)(U + 27262976);     // 8,388,608
    // total = 21,495,808 + 35,651,584 = 57,147,392 B

    // ---- embed + rope + one-time weight conversions ----
    embed_kernel<<<NROW, 192, 0, stream>>>(tokens, emb, x0, x);
    rope_kernel<<<64, 256, 0, stream>>>(ropec, ropes);
    wconv<<<dim3(1024/32, 768/32), 256, 0, stream>>>(head_w,    wheadT,  768,  1024);
    wconv<<<dim3(2304/32, 256/32), 256, 0, stream>>>(sa_qkv_w,  wsaqkvT, 256,  2304);
    wconv<<<dim3( 256/32, 768/32), 256, 0, stream>>>(sa_proj_w, wsaprojT,768,  256);
    wconv<<<dim3(1024/32, 256/32), 256, 0, stream>>>(sa_ff_w1,  wsaff1T, 256,  1024);
    wconv<<<dim3( 256/32,1024/32), 256, 0, stream>>>(sa_ff_w2,  wsaff2T, 1024, 256);

    // ---- 4 main layers ----
    for(int i = 0; i < 4; i++){
        wconv<<<dim3(2304/32, 768/32), 256, 0, stream>>>(qkv_w + (size_t)i*EDIM*3*EDIM, wqkvT, 768, 2304);
        wconv<<<dim3(3072/32, 768/32), 256, 0, stream>>>(ff_w1 + (size_t)i*EDIM*4*EDIM, wff1T, 768, 3072);
        wconv<<<dim3( 768/32,3072/32), 256, 0, stream>>>(ff_w2 + (size_t)i*4*EDIM*EDIM, wff2T, 3072, 768);

        ln_kernel<<<NROW, 256, 0, stream>>>(x, nullptr, bl0g + i*EDIM, bl0b + i*EDIM, h, EDIM);
        gemm128<0,0,1><<<dim3(18, 8), 256, 0, stream>>>(
            (const short*)h, (const short*)wqkvT, nullptr, nullptr, qkv, NROW, 3*EDIM, EDIM);
        rope_qkv<<<NROW, 256, 0, stream>>>(qkv, ropec, ropes, qrb, krb, vvb);
        dim3 agrid(TSEQ/4, NHEAD, BB);
        if(i == 0)      patch_attn2<16><<<agrid, 256, 0, stream>>>(qrb, krb, vvb, x);
        else if(i == 1) patch_attn2<32><<<agrid, 256, 0, stream>>>(qrb, krb, vvb, x);
        else if(i == 2) patch_attn2<64><<<agrid, 256, 0, stream>>>(qrb, krb, vvb, x);
        else            patch_attn2<128><<<agrid, 256, 0, stream>>>(qrb, krb, vvb, x);
        ln_kernel<<<NROW, 256, 0, stream>>>(x, nullptr, bl1g + i*EDIM, bl1b + i*EDIM, h, EDIM);
        gemm128<1,0,1><<<dim3(24, 8), 256, 0, stream>>>(
            (const short*)h, (const short*)wff1T, ff_b1 + (size_t)i*4*EDIM, nullptr, ff1, NROW, 4*EDIM, EDIM);
        gemm64t<0,1,0><<<dim3(12, 16), 256, 0, stream>>>(
            (const short*)ff1, (const short*)wff2T, ff_b2 + (size_t)i*EDIM, x, x, NROW, EDIM, 4*EDIM);
    }

    // ---- final LN(x0 + x) + head ----
    ln_kernel<<<NROW, 256, 0, stream>>>(x, x0, fin_g, fin_b, h, EDIM);
    gemm64t<0,0,0><<<dim3(16, 16), 256, 0, stream>>>(
        (const short*)h, (const short*)wheadT, head_b, nullptr, logits, NROW, PDIM*VDIM, EDIM);

    // ---- sa block over (B*T*P, V) ----
    ln_kernel<<<NROW2, 256, 0, stream>>>(logits, nullptr, sa_ln0_g, sa_ln0_b, h2, VDIM);
    gemm128<0,0,1><<<dim3(18, 32), 256, 0, stream>>>(
        (const short*)h2, (const short*)wsaqkvT, nullptr, nullptr, qkv2, NROW2, 3*EDIM, VDIM);
    sa_attn<<<dim3(TSEQ, NHEAD, BB), 256, 0, stream>>>(qkv2, sa_o);
    gemm64t<0,1,0><<<dim3(4, 64), 256, 0, stream>>>(
        (const short*)sa_o, (const short*)wsaprojT, sa_proj_b, logits, logits, NROW2, VDIM, EDIM);
    ln_kernel<<<NROW2, 256, 0, stream>>>(logits, nullptr, sa_ln1_g, sa_ln1_b, h2, VDIM);
    gemm128<1,0,1><<<dim3(8, 32), 256, 0, stream>>>(
        (const short*)h2, (const short*)wsaff1T, sa_ff_b1, nullptr, sa_f1, NROW2, 4*VDIM, VDIM);
    gemm64t<0,1,0><<<dim3(4, 64), 256, 0, stream>>>(
        (const short*)sa_f1, (const short*)wsaff2T, sa_ff_b2, logits, logits, NROW2, VDIM, 4*VDIM);

    // ---- output: p = 0 slice ----
    outcopy<<<(out_size + 255)/256, 256, 0, stream>>>(logits, out);
}

// Round 5
// 736.515 us; speedup vs baseline: 3.4494x; 1.1574x over previous
//
#include <hip/hip_runtime.h>
#include <hip/hip_bf16.h>
#include <cstdint>
#include <cstddef>

// Model dims (fixed by the problem)
#define BB    2
#define TSEQ  512
#define EDIM  768
#define NHEAD 12
#define HDIM  64
#define VDIM  256
#define PDIM  4
#define NROW  (BB*TSEQ)        // 1024
#define NROW2 (BB*TSEQ*PDIM)   // 4096

typedef __attribute__((ext_vector_type(8))) short short8;
typedef __attribute__((ext_vector_type(4))) float floatx4;

__device__ __forceinline__ float gelu_f(float v){
    return 0.5f * v * (1.0f + erff(v * 0.70710678118654752f));
}

__device__ __forceinline__ float b2f(short s){
    unsigned u = ((unsigned)(unsigned short)s) << 16;
    float f; __builtin_memcpy(&f, &u, 4); return f;
}

__device__ __forceinline__ void gload16(const void* g, void* l){
    __builtin_amdgcn_global_load_lds((const __attribute__((address_space(1))) void*)g,
                                     (__attribute__((address_space(3))) void*)l, 16, 0, 0);
}

// ---------------------------------------------------------------------------
// Multi-weight convert+transpose: fp32 [K,N] -> bf16 [N,K], up to 5 weights
// per dispatch (flat 1-D grid over 32x32 tiles).
// ---------------------------------------------------------------------------
struct WD { const float* in; __hip_bfloat16* out; int K; int N; int ntiles; };

__global__ __launch_bounds__(256) void wconv_multi(WD d0, WD d1, WD d2, WD d3, WD d4)
{
    int id = blockIdx.x;
    WD w = d0;
    if(id >= w.ntiles){ id -= w.ntiles; w = d1;
        if(id >= w.ntiles){ id -= w.ntiles; w = d2;
            if(id >= w.ntiles){ id -= w.ntiles; w = d3;
                if(id >= w.ntiles){ id -= w.ntiles; w = d4; } } } }
    if(!w.in) return;
    const int tx = w.N / 32;
    const int n0 = (id % tx) * 32, k0 = (id / tx) * 32;
    __shared__ float t[32][33];
    const int c = threadIdx.x & 31, r0 = threadIdx.x >> 5;
    #pragma unroll
    for(int r = r0; r < 32; r += 8)
        t[r][c] = w.in[(size_t)(k0 + r) * w.N + n0 + c];
    __syncthreads();
    #pragma unroll
    for(int r = r0; r < 32; r += 8)
        w.out[(size_t)(n0 + r) * w.K + k0 + c] = __float2bfloat16(t[c][r]);
}

// ---------------------------------------------------------------------------
// MFMA GEMM 128x128 (m97 structure): C = op(A @ Bt^T (+bias)) (+resid)
// ROPESA=1: epilogue rotates q/k cols (RoPE at position p=row%4) before store.
// ---------------------------------------------------------------------------
template<int ACT, int RESID, int OUTBF16, int ROPESA>
__global__ __launch_bounds__(256) void gemm128(
    const short* __restrict__ A, const short* __restrict__ Bt,
    const float* __restrict__ bias, const float* __restrict__ resid,
    void* __restrict__ Cout, const float* __restrict__ rc, const float* __restrict__ rs,
    int M, int N, int K)
{
    alignas(16) __shared__ short As[128*32];
    alignas(16) __shared__ short Bs[128*32];
    const int tid  = threadIdx.x;
    const int lane = tid & 63;
    const int wave = tid >> 6;
    const int bm = blockIdx.y * 128, bn = blockIdx.x * 128;
    const int wm = (wave >> 1) * 64, wn = (wave & 1) * 64;
    const int quad = lane >> 4, l16 = lane & 15;

    floatx4 acc[4][4];
    #pragma unroll
    for(int i = 0; i < 4; i++)
        #pragma unroll
        for(int j = 0; j < 4; j++)
            acc[i][j] = floatx4{0.f, 0.f, 0.f, 0.f};

    const int r  = tid >> 2;
    const int c8 = (tid & 3) * 8;
    const int ldsoff = (tid & 192) * 16;

    for(int k0 = 0; k0 < K; k0 += 32){
        gload16(A  + (size_t)(bm + r     ) * K + k0 + c8, (char*)As + ldsoff);
        gload16(A  + (size_t)(bm + r + 64) * K + k0 + c8, (char*)As + 4096 + ldsoff);
        gload16(Bt + (size_t)(bn + r     ) * K + k0 + c8, (char*)Bs + ldsoff);
        gload16(Bt + (size_t)(bn + r + 64) * K + k0 + c8, (char*)Bs + 4096 + ldsoff);
        __syncthreads();
        short8 af[4], bfr[4];
        #pragma unroll
        for(int i = 0; i < 4; i++){
            af[i]  = *(const short8*)&As[(wm + i*16 + l16)*32 + quad*8];
            bfr[i] = *(const short8*)&Bs[(wn + i*16 + l16)*32 + quad*8];
        }
        #pragma unroll
        for(int i = 0; i < 4; i++)
            #pragma unroll
            for(int j = 0; j < 4; j++)
                acc[i][j] = __builtin_amdgcn_mfma_f32_16x16x32_bf16(af[i], bfr[j], acc[i][j], 0, 0, 0);
        __syncthreads();
    }

    float* Cf = (float*)Cout;
    __hip_bfloat16* Cb = (__hip_bfloat16*)Cout;

    if(ROPESA){
        // wave covers 64 cols = one head-aligned group; region: 0=q,1=k,2=v
        const int hb = bn + wn;
        const int region = hb / 768;
        #pragma unroll
        for(int i = 0; i < 4; i++){
            #pragma unroll
            for(int rr = 0; rr < 4; rr++){
                int row = bm + wm + i*16 + quad*4 + rr;
                float a0 = acc[i][0][rr], a1 = acc[i][1][rr];
                float a2 = acc[i][2][rr], a3 = acc[i][3][rr];
                size_t rowb = (size_t)row * N + hb;
                if(region == 2){
                    Cb[rowb + l16]      = __float2bfloat16(a0);
                    Cb[rowb + 16 + l16] = __float2bfloat16(a1);
                    Cb[rowb + 32 + l16] = __float2bfloat16(a2);
                    Cb[rowb + 48 + l16] = __float2bfloat16(a3);
                }else{
                    int p = row & 3;
                    float c0 = rc[p*32 + l16],      s0 = rs[p*32 + l16];
                    float c1 = rc[p*32 + 16 + l16], s1 = rs[p*32 + 16 + l16];
                    Cb[rowb + l16]      = __float2bfloat16(a0*c0 - a2*s0);
                    Cb[rowb + 16 + l16] = __float2bfloat16(a1*c1 - a3*s1);
                    Cb[rowb + 32 + l16] = __float2bfloat16(a0*s0 + a2*c0);
                    Cb[rowb + 48 + l16] = __float2bfloat16(a1*s1 + a3*c1);
                }
            }
        }
        return;
    }

    #pragma unroll
    for(int i = 0; i < 4; i++){
        int row0 = bm + wm + i*16 + quad*4;
        #pragma unroll
        for(int j = 0; j < 4; j++){
            int col = bn + wn + j*16 + l16;
            float bv = bias ? bias[col] : 0.f;
            #pragma unroll
            for(int rr = 0; rr < 4; rr++){
                float v = acc[i][j][rr] + bv;
                if(ACT) v = gelu_f(v);
                if(RESID) v += resid[(size_t)(row0 + rr) * N + col];
                if(OUTBF16) Cb[(size_t)(row0 + rr) * N + col] = __float2bfloat16(v);
                else        Cf[(size_t)(row0 + rr) * N + col] = v;
            }
        }
    }
}

// ---------------------------------------------------------------------------
// MFMA GEMM 64x128. EPI: 0 = bias bf16 store, 1 = bias+gelu bf16 store,
// 2 = phase-1 qkv: RoPE-rotate q/k and write head-major qrb/krb/vvb.
// ---------------------------------------------------------------------------
template<int EPI>
__global__ __launch_bounds__(256) void gemm64x128(
    const short* __restrict__ A, const short* __restrict__ Bt,
    const float* __restrict__ bias, __hip_bfloat16* __restrict__ Cout,
    __hip_bfloat16* __restrict__ qrb, __hip_bfloat16* __restrict__ krb,
    __hip_bfloat16* __restrict__ vvb,
    const float* __restrict__ rc, const float* __restrict__ rs,
    int M, int N, int K)
{
    alignas(16) __shared__ short As[64*32];
    alignas(16) __shared__ short Bs[128*32];
    const int tid  = threadIdx.x;
    const int lane = tid & 63;
    const int wave = tid >> 6;
    const int bm = blockIdx.y * 64, bn = blockIdx.x * 128;
    const int wm = (wave >> 1) * 32, wn = (wave & 1) * 64;
    const int quad = lane >> 4, l16 = lane & 15;

    floatx4 acc[2][4];
    #pragma unroll
    for(int i = 0; i < 2; i++)
        #pragma unroll
        for(int j = 0; j < 4; j++)
            acc[i][j] = floatx4{0.f, 0.f, 0.f, 0.f};

    const int r  = tid >> 2;
    const int c8 = (tid & 3) * 8;
    const int ldsoff = (tid & 192) * 16;

    for(int k0 = 0; k0 < K; k0 += 32){
        gload16(A  + (size_t)(bm + r     ) * K + k0 + c8, (char*)As + ldsoff);
        gload16(Bt + (size_t)(bn + r     ) * K + k0 + c8, (char*)Bs + ldsoff);
        gload16(Bt + (size_t)(bn + r + 64) * K + k0 + c8, (char*)Bs + 4096 + ldsoff);
        __syncthreads();
        short8 af[2], bfr[4];
        #pragma unroll
        for(int i = 0; i < 2; i++)
            af[i]  = *(const short8*)&As[(wm + i*16 + l16)*32 + quad*8];
        #pragma unroll
        for(int j = 0; j < 4; j++)
            bfr[j] = *(const short8*)&Bs[(wn + j*16 + l16)*32 + quad*8];
        #pragma unroll
        for(int i = 0; i < 2; i++)
            #pragma unroll
            for(int j = 0; j < 4; j++)
                acc[i][j] = __builtin_amdgcn_mfma_f32_16x16x32_bf16(af[i], bfr[j], acc[i][j], 0, 0, 0);
        __syncthreads();
    }

    if(EPI == 2){
        const int hb = bn + wn;            // col base of this wave's 64 cols
        const int region = hb / 768;       // 0=q, 1=k, 2=v
        const int h = (hb % 768) >> 6;
        #pragma unroll
        for(int i = 0; i < 2; i++){
            #pragma unroll
            for(int rr = 0; rr < 4; rr++){
                int row = bm + wm + i*16 + quad*4 + rr;
                int t = row & (TSEQ-1), b = row >> 9;
                float a0 = acc[i][0][rr], a1 = acc[i][1][rr];
                float a2 = acc[i][2][rr], a3 = acc[i][3][rr];
                size_t dbase = ((size_t)(b*NHEAD + h)*TSEQ + t)*HDIM;
                if(region == 2){
                    vvb[dbase + l16]      = __float2bfloat16(a0);
                    vvb[dbase + 16 + l16] = __float2bfloat16(a1);
                    vvb[dbase + 32 + l16] = __float2bfloat16(a2);
                    vvb[dbase + 48 + l16] = __float2bfloat16(a3);
                }else{
                    float c0 = rc[t*32 + l16],      s0 = rs[t*32 + l16];
                    float c1 = rc[t*32 + 16 + l16], s1 = rs[t*32 + 16 + l16];
                    __hip_bfloat16* dst = (region == 0) ? qrb : krb;
                    dst[dbase + l16]      = __float2bfloat16(a0*c0 - a2*s0);
                    dst[dbase + 16 + l16] = __float2bfloat16(a1*c1 - a3*s1);
                    dst[dbase + 32 + l16] = __float2bfloat16(a0*s0 + a2*c0);
                    dst[dbase + 48 + l16] = __float2bfloat16(a1*s1 + a3*c1);
                }
            }
        }
        return;
    }

    #pragma unroll
    for(int i = 0; i < 2; i++){
        int row0 = bm + wm + i*16 + quad*4;
        #pragma unroll
        for(int j = 0; j < 4; j++){
            int col = bn + wn + j*16 + l16;
            float bv = bias ? bias[col] : 0.f;
            #pragma unroll
            for(int rr = 0; rr < 4; rr++){
                float v = acc[i][j][rr] + bv;
                if(EPI == 1) v = gelu_f(v);
                Cout[(size_t)(row0 + rr) * N + col] = __float2bfloat16(v);
            }
        }
    }
}

// ---------------------------------------------------------------------------
// 64x64-tile GEMM for small-N layers.
// ---------------------------------------------------------------------------
template<int ACT, int RESID, int OUTBF16>
__global__ __launch_bounds__(256) void gemm64t(
    const short* __restrict__ A, const short* __restrict__ Bt,
    const float* __restrict__ bias, const float* __restrict__ resid,
    void* __restrict__ Cout, int M, int N, int K)
{
    alignas(16) __shared__ short As[64*32];
    alignas(16) __shared__ short Bs[64*32];
    const int tid  = threadIdx.x;
    const int lane = tid & 63;
    const int wave = tid >> 6;
    const int bm = blockIdx.y * 64, bn = blockIdx.x * 64;
    const int wm = (wave >> 1) * 32, wn = (wave & 1) * 32;
    const int quad = lane >> 4, l16 = lane & 15;

    floatx4 acc[2][2];
    #pragma unroll
    for(int i = 0; i < 2; i++)
        #pragma unroll
        for(int j = 0; j < 2; j++)
            acc[i][j] = floatx4{0.f, 0.f, 0.f, 0.f};

    const int r  = tid >> 2;
    const int c8 = (tid & 3) * 8;
    const int ldsoff = (tid & 192) * 16;

    for(int k0 = 0; k0 < K; k0 += 32){
        gload16(A  + (size_t)(bm + r) * K + k0 + c8, (char*)As + ldsoff);
        gload16(Bt + (size_t)(bn + r) * K + k0 + c8, (char*)Bs + ldsoff);
        __syncthreads();
        short8 af[2], bfr[2];
        #pragma unroll
        for(int i = 0; i < 2; i++){
            af[i]  = *(const short8*)&As[(wm + i*16 + l16)*32 + quad*8];
            bfr[i] = *(const short8*)&Bs[(wn + i*16 + l16)*32 + quad*8];
        }
        #pragma unroll
        for(int i = 0; i < 2; i++)
            #pragma unroll
            for(int j = 0; j < 2; j++)
                acc[i][j] = __builtin_amdgcn_mfma_f32_16x16x32_bf16(af[i], bfr[j], acc[i][j], 0, 0, 0);
        __syncthreads();
    }

    float* Cf = (float*)Cout;
    __hip_bfloat16* Cb = (__hip_bfloat16*)Cout;
    #pragma unroll
    for(int i = 0; i < 2; i++){
        int row0 = bm + wm + i*16 + quad*4;
        #pragma unroll
        for(int j = 0; j < 2; j++){
            int col = bn + wn + j*16 + l16;
            float bv = bias ? bias[col] : 0.f;
            #pragma unroll
            for(int rr = 0; rr < 4; rr++){
                float v = acc[i][j][rr] + bv;
                if(ACT) v = gelu_f(v);
                if(RESID) v += resid[(size_t)(row0 + rr) * N + col];
                if(OUTBF16) Cb[(size_t)(row0 + rr) * N + col] = __float2bfloat16(v);
                else        Cf[(size_t)(row0 + rr) * N + col] = v;
            }
        }
    }
}

// ---------------------------------------------------------------------------
// LayerNorm over last dim D. fp32 in, bf16 out.
// ---------------------------------------------------------------------------
__global__ __launch_bounds__(256) void ln_kernel(
    const float* __restrict__ in, const float* __restrict__ in2,
    const float* __restrict__ g, const float* __restrict__ bta,
    __hip_bfloat16* __restrict__ out, int D)
{
    const int row = blockIdx.x;
    const float* xr  = in + (size_t)row * D;
    const float* x2r = in2 ? in2 + (size_t)row * D : nullptr;
    const int tid = threadIdx.x;
    const int nper = D / 256;
    float vals[3];
    float sum = 0.f, sq = 0.f;
    for(int i = 0; i < nper; i++){
        int d = tid + i*256;
        float v = xr[d];
        if(x2r) v += x2r[d];
        vals[i] = v; sum += v; sq += v*v;
    }
    #pragma unroll
    for(int off = 32; off > 0; off >>= 1){
        sum += __shfl_xor(sum, off, 64);
        sq  += __shfl_xor(sq,  off, 64);
    }
    __shared__ float ssum[4], ssq[4];
    __shared__ float smean, srstd;
    int wid = tid >> 6;
    if((tid & 63) == 0){ ssum[wid] = sum; ssq[wid] = sq; }
    __syncthreads();
    if(tid == 0){
        float S = 0.f, Q = 0.f;
        for(int w = 0; w < 4; w++){ S += ssum[w]; Q += ssq[w]; }
        float m = S / D;
        float var = Q / D - m*m;
        smean = m;
        srstd = rsqrtf(fmaxf(var, 0.f) + 1e-5f);
    }
    __syncthreads();
    float m = smean, rs2 = srstd;
    for(int i = 0; i < nper; i++){
        int d = tid + i*256;
        out[(size_t)row*D + d] = __float2bfloat16((vals[i] - m) * rs2 * g[d] + bta[d]);
    }
}

// ---------------------------------------------------------------------------
__global__ __launch_bounds__(192) void embed_kernel(
    const int* __restrict__ tokens, const float* __restrict__ emb,
    float* __restrict__ x0, float* __restrict__ x)
{
    const int row = blockIdx.x;
    const int tok = tokens[row];
    const float4* src = (const float4*)(emb + (size_t)tok * EDIM);
    float4* d0 = (float4*)(x0 + (size_t)row * EDIM);
    float4* d1 = (float4*)(x  + (size_t)row * EDIM);
    for(int i = threadIdx.x; i < EDIM/4; i += blockDim.x){
        float4 v = src[i]; d0[i] = v; d1[i] = v;
    }
}

// ---------------------------------------------------------------------------
__global__ __launch_bounds__(256) void rope_kernel(float* __restrict__ rc, float* __restrict__ rs)
{
    int i = blockIdx.x * 256 + threadIdx.x;   // 512*32 = 16384
    int pos = i >> 5, d = i & 31;
    float inv = powf(10000.0f, -(float)(2*d) / 64.0f);
    float f = (float)pos * inv;
    rc[i] = cosf(f);
    rs[i] = sinf(f);
}

// ---------------------------------------------------------------------------
// Sliding-window attention. 4 waves/block = 4 consecutive queries.
// K/V window staged in LDS with 16B XOR-swizzled chunks. Residual add into x.
// ---------------------------------------------------------------------------
template<int S>
__global__ __launch_bounds__(256) void patch_attn2(
    const __hip_bfloat16* __restrict__ qr, const __hip_bfloat16* __restrict__ kr,
    const __hip_bfloat16* __restrict__ vv, float* __restrict__ x)
{
    constexpr int W = S + 3;               // staged window rows
    alignas(16) __shared__ short Ks[W*64];
    alignas(16) __shared__ short Vs[W*64];
    __shared__ float qlds[4*64];
    __shared__ float pb[4*128];

    const int t0 = blockIdx.x * 4;
    const int h = blockIdx.y, b = blockIdx.z;
    const int tid = threadIdx.x;
    const int wv = tid >> 6, lane = tid & 63;
    const size_t headbase = ((size_t)(b*NHEAD + h)) * TSEQ;

    const int c = tid & 7;
    for(int r = tid >> 3; r < W; r += 32){
        int g = t0 - S + 1 + r;
        int gc = g < 0 ? 0 : g;
        int sc = (c ^ (r & 7)) * 8;
        *(short8*)&Ks[r*64 + sc] = *(const short8*)((const short*)kr + (headbase + gc)*64 + c*8);
        *(short8*)&Vs[r*64 + sc] = *(const short8*)((const short*)vv + (headbase + gc)*64 + c*8);
    }
    qlds[wv*64 + lane] = __bfloat162float(qr[(headbase + t0 + wv)*64 + lane]);
    __syncthreads();

    const int t = t0 + wv;
    const int r0 = (S >= 64) ? (wv + lane) : ((lane < S) ? (wv + lane) : 0);
    const int r1 = wv + lane + 64;
    float a0 = 0.f, a1 = 0.f;
    #pragma unroll
    for(int ch = 0; ch < 8; ch++){
        float4 qa = *(const float4*)&qlds[wv*64 + ch*8];
        float4 qb = *(const float4*)&qlds[wv*64 + ch*8 + 4];
        short8 k0 = *(const short8*)&Ks[r0*64 + ((ch ^ (r0 & 7))*8)];
        a0 += qa.x*b2f(k0[0]) + qa.y*b2f(k0[1]) + qa.z*b2f(k0[2]) + qa.w*b2f(k0[3])
            + qb.x*b2f(k0[4]) + qb.y*b2f(k0[5]) + qb.z*b2f(k0[6]) + qb.w*b2f(k0[7]);
        if(S == 128){
            short8 k1 = *(const short8*)&Ks[r1*64 + ((ch ^ (r1 & 7))*8)];
            a1 += qa.x*b2f(k1[0]) + qa.y*b2f(k1[1]) + qa.z*b2f(k1[2]) + qa.w*b2f(k1[3])
                + qb.x*b2f(k1[4]) + qb.y*b2f(k1[5]) + qb.z*b2f(k1[6]) + qb.w*b2f(k1[7]);
        }
    }
    const int key0 = t - S + 1 + lane;
    const bool v0 = (lane < S) && (key0 >= 0);
    const bool v1 = (S == 128) && (key0 + 64 >= 0);
    float s0 = v0 ? a0 * 0.125f : -1e30f;
    float s1 = v1 ? a1 * 0.125f : -1e30f;
    float mx = fmaxf(s0, s1);
    #pragma unroll
    for(int off = 32; off > 0; off >>= 1) mx = fmaxf(mx, __shfl_xor(mx, off, 64));
    float p0 = v0 ? expf(s0 - mx) : 0.f;
    float p1 = v1 ? expf(s1 - mx) : 0.f;
    float sm = p0 + p1;
    #pragma unroll
    for(int off = 32; off > 0; off >>= 1) sm += __shfl_xor(sm, off, 64);
    const float inv = 1.f / sm;
    pb[wv*128 + lane] = p0 * inv;
    if(S == 128) pb[wv*128 + lane + 64] = p1 * inv;
    __syncthreads();

    const int d = lane;
    const int coff = d >> 3, dlo = d & 7;
    float o = 0.f;
    #pragma unroll 8
    for(int j = 0; j < S; j++){
        int r = wv + j;
        float p = pb[wv*128 + j];
        o += p * b2f(Vs[r*64 + ((coff ^ (r & 7))*8) + dlo]);
    }
    x[((size_t)(b*TSEQ) + t) * EDIM + h*HDIM + d] += o;
}

// ---------------------------------------------------------------------------
// P-axis attention: q/k already RoPE-rotated by the sa-qkv GEMM epilogue.
// ---------------------------------------------------------------------------
__global__ __launch_bounds__(256) void sa_attn(
    const __hip_bfloat16* __restrict__ qkv2, __hip_bfloat16* __restrict__ o)
{
    const int t = blockIdx.x, h = blockIdx.y, b = blockIdx.z;
    const int p = threadIdx.x >> 6, lane = threadIdx.x & 63;
    const int row0 = (b*TSEQ + t) * PDIM;
    const short* base = (const short*)qkv2 + (size_t)row0 * (3*EDIM);
    const int d = lane;
    float q = b2f(base[(size_t)p*(3*EDIM) + h*HDIM + d]);
    float sc[4];
    #pragma unroll
    for(int j = 0; j < 4; j++){
        float kj = b2f(base[(size_t)j*(3*EDIM) + EDIM + h*HDIM + d]);
        float v = q * kj;
        #pragma unroll
        for(int off = 32; off > 0; off >>= 1) v += __shfl_xor(v, off, 64);
        sc[j] = v * 0.125f;
    }
    float m = fmaxf(fmaxf(sc[0], sc[1]), fmaxf(sc[2], sc[3]));
    float e0 = expf(sc[0]-m), e1 = expf(sc[1]-m), e2 = expf(sc[2]-m), e3 = expf(sc[3]-m);
    float idn = 1.f / (e0 + e1 + e2 + e3);
    float ov = (e0 * b2f(base[0*(3*EDIM) + 2*EDIM + h*HDIM + d])
              + e1 * b2f(base[1*(3*EDIM) + 2*EDIM + h*HDIM + d])
              + e2 * b2f(base[2*(3*EDIM) + 2*EDIM + h*HDIM + d])
              + e3 * b2f(base[3*(3*EDIM) + 2*EDIM + h*HDIM + d])) * idn;
    o[(size_t)(row0 + p) * EDIM + h*HDIM + d] = __float2bfloat16(ov);
}

// ---------------------------------------------------------------------------
__global__ __launch_bounds__(256) void outcopy(const float* __restrict__ x2, float* __restrict__ out)
{
    int i = blockIdx.x * 256 + threadIdx.x;    // B*T*V = 262144
    int row = i >> 8, col = i & 255;
    out[i] = x2[(size_t)row * PDIM * VDIM + col];
}

// ---------------------------------------------------------------------------
extern "C" void kernel_launch(void* const* d_in, const int* in_sizes, int n_in,
                              void* d_out, int out_size, void* d_ws, size_t ws_size,
                              hipStream_t stream)
{
    const int*   tokens    = (const int*)  d_in[0];
    const float* emb       = (const float*)d_in[1];
    const float* bl0g      = (const float*)d_in[2];
    const float* bl0b      = (const float*)d_in[3];
    const float* bl1g      = (const float*)d_in[4];
    const float* bl1b      = (const float*)d_in[5];
    const float* qkv_w     = (const float*)d_in[6];
    const float* ff_w1     = (const float*)d_in[7];
    const float* ff_b1     = (const float*)d_in[8];
    const float* ff_w2     = (const float*)d_in[9];
    const float* ff_b2     = (const float*)d_in[10];
    const float* fin_g     = (const float*)d_in[11];
    const float* fin_b     = (const float*)d_in[12];
    const float* head_w    = (const float*)d_in[13];
    const float* head_b    = (const float*)d_in[14];
    const float* sa_ln0_g  = (const float*)d_in[15];
    const float* sa_ln0_b  = (const float*)d_in[16];
    const float* sa_ln1_g  = (const float*)d_in[17];
    const float* sa_ln1_b  = (const float*)d_in[18];
    const float* sa_qkv_w  = (const float*)d_in[19];
    const float* sa_proj_w = (const float*)d_in[20];
    const float* sa_proj_b = (const float*)d_in[21];
    const float* sa_ff_w1  = (const float*)d_in[22];
    const float* sa_ff_b1  = (const float*)d_in[23];
    const float* sa_ff_w2  = (const float*)d_in[24];
    const float* sa_ff_b2  = (const float*)d_in[25];
    float* out = (float*)d_out;

    // ---- workspace layout (byte offsets) ----
    char* base = (char*)d_ws;
    float* logits           = (float*)(base);                    // 4,194,304
    float* ropec            = (float*)(base + 4194304);          //    65,536
    float* ropes            = (float*)(base + 4259840);          //    65,536
    __hip_bfloat16* wqkvT   = (__hip_bfloat16*)(base + 4325376); // 3,538,944 (per-layer, reused)
    __hip_bfloat16* wff1T   = (__hip_bfloat16*)(base + 7864320); // 4,718,592
    __hip_bfloat16* wff2T   = (__hip_bfloat16*)(base + 12582912);// 4,718,592
    __hip_bfloat16* wheadT  = (__hip_bfloat16*)(base + 17301504);// 1,572,864
    __hip_bfloat16* wsaqkvT = (__hip_bfloat16*)(base + 18874368);// 1,179,648
    __hip_bfloat16* wsaprojT= (__hip_bfloat16*)(base + 20054016);//   393,216
    __hip_bfloat16* wsaff1T = (__hip_bfloat16*)(base + 20447232);//   524,288
    __hip_bfloat16* wsaff2T = (__hip_bfloat16*)(base + 20971520);//   524,288
    char* U = base + 21495808;
    // phase 1
    float* x0           = (float*)(U);                           // 3,145,728
    float* x            = (float*)(U + 3145728);                 // 3,145,728
    __hip_bfloat16* h   = (__hip_bfloat16*)(U + 6291456);        // 1,572,864
    __hip_bfloat16* ff1 = (__hip_bfloat16*)(U + 12582912);       // 6,291,456
    __hip_bfloat16* qrb = (__hip_bfloat16*)(U + 18874368);       // 1,572,864
    __hip_bfloat16* krb = (__hip_bfloat16*)(U + 20447232);       // 1,572,864
    __hip_bfloat16* vvb = (__hip_bfloat16*)(U + 22020096);       // 1,572,864
    // phase 2 (aliases phase 1, dead by then)
    __hip_bfloat16* h2    = (__hip_bfloat16*)(U);                // 2,097,152
    __hip_bfloat16* qkv2  = (__hip_bfloat16*)(U + 2097152);      // 18,874,368
    __hip_bfloat16* sa_o  = (__hip_bfloat16*)(U + 20971520);     // 6,291,456
    __hip_bfloat16* sa_f1 = (__hip_bfloat16*)(U + 27262976);     // 8,388,608
    // total = 21,495,808 + 35,651,584 = 57,147,392 B

    // ---- embed + rope + phase-2 weight conversions (one dispatch) ----
    embed_kernel<<<NROW, 192, 0, stream>>>(tokens, emb, x0, x);
    rope_kernel<<<64, 256, 0, stream>>>(ropec, ropes);
    {
        WD dh  = { head_w,    wheadT,   768,  1024, (1024/32)*( 768/32) }; // 768
        WD dq  = { sa_qkv_w,  wsaqkvT,  256,  2304, (2304/32)*( 256/32) }; // 576
        WD dp  = { sa_proj_w, wsaprojT, 768,   256, ( 256/32)*( 768/32) }; // 192
        WD df1 = { sa_ff_w1,  wsaff1T,  256,  1024, (1024/32)*( 256/32) }; // 256
        WD df2 = { sa_ff_w2,  wsaff2T, 1024,   256, ( 256/32)*(1024/32) }; // 256
        wconv_multi<<<768+576+192+256+256, 256, 0, stream>>>(dh, dq, dp, df1, df2);
    }

    // ---- 4 main layers ----
    for(int i = 0; i < 4; i++){
        {
            WD dq  = { qkv_w + (size_t)i*EDIM*3*EDIM, wqkvT, 768, 2304, (2304/32)*(768/32) }; // 1728
            WD df1 = { ff_w1 + (size_t)i*EDIM*4*EDIM, wff1T, 768, 3072, (3072/32)*(768/32) }; // 2304
            WD df2 = { ff_w2 + (size_t)i*4*EDIM*EDIM, wff2T, 3072, 768, ( 768/32)*(3072/32)}; // 2304
            WD dn  = { nullptr, nullptr, 0, 0, 0 };
            wconv_multi<<<1728+2304+2304, 256, 0, stream>>>(dq, df1, df2, dn, dn);
        }
        ln_kernel<<<NROW, 256, 0, stream>>>(x, nullptr, bl0g + i*EDIM, bl0b + i*EDIM, h, EDIM);
        // qkv GEMM with fused RoPE + head-major scatter
        gemm64x128<2><<<dim3(18, 16), 256, 0, stream>>>(
            (const short*)h, (const short*)wqkvT, nullptr, nullptr,
            qrb, krb, vvb, ropec, ropes, NROW, 3*EDIM, EDIM);
        dim3 agrid(TSEQ/4, NHEAD, BB);
        if(i == 0)      patch_attn2<16><<<agrid, 256, 0, stream>>>(qrb, krb, vvb, x);
        else if(i == 1) patch_attn2<32><<<agrid, 256, 0, stream>>>(qrb, krb, vvb, x);
        else if(i == 2) patch_attn2<64><<<agrid, 256, 0, stream>>>(qrb, krb, vvb, x);
        else            patch_attn2<128><<<agrid, 256, 0, stream>>>(qrb, krb, vvb, x);
        ln_kernel<<<NROW, 256, 0, stream>>>(x, nullptr, bl1g + i*EDIM, bl1b + i*EDIM, h, EDIM);
        gemm64x128<1><<<dim3(24, 16), 256, 0, stream>>>(
            (const short*)h, (const short*)wff1T, ff_b1 + (size_t)i*4*EDIM, ff1,
            nullptr, nullptr, nullptr, nullptr, nullptr, NROW, 4*EDIM, EDIM);
        gemm64t<0,1,0><<<dim3(12, 16), 256, 0, stream>>>(
            (const short*)ff1, (const short*)wff2T, ff_b2 + (size_t)i*EDIM, x, x, NROW, EDIM, 4*EDIM);
    }

    // ---- final LN(x0 + x) + head ----
    ln_kernel<<<NROW, 256, 0, stream>>>(x, x0, fin_g, fin_b, h, EDIM);
    gemm64t<0,0,0><<<dim3(16, 16), 256, 0, stream>>>(
        (const short*)h, (const short*)wheadT, head_b, nullptr, logits, NROW, PDIM*VDIM, EDIM);

    // ---- sa block over (B*T*P, V) ----
    ln_kernel<<<NROW2, 256, 0, stream>>>(logits, nullptr, sa_ln0_g, sa_ln0_b, h2, VDIM);
    gemm128<0,0,1,1><<<dim3(18, 32), 256, 0, stream>>>(
        (const short*)h2, (const short*)wsaqkvT, nullptr, nullptr, qkv2,
        ropec, ropes, NROW2, 3*EDIM, VDIM);
    sa_attn<<<dim3(TSEQ, NHEAD, BB), 256, 0, stream>>>(qkv2, sa_o);
    gemm64t<0,1,0><<<dim3(4, 64), 256, 0, stream>>>(
        (const short*)sa_o, (const short*)wsaprojT, sa_proj_b, logits, logits, NROW2, VDIM, EDIM);
    ln_kernel<<<NROW2, 256, 0, stream>>>(logits, nullptr, sa_ln1_g, sa_ln1_b, h2, VDIM);
    gemm128<1,0,1,0><<<dim3(8, 32), 256, 0, stream>>>(
        (const short*)h2, (const short*)wsaff1T, sa_ff_b1, nullptr, sa_f1,
        nullptr, nullptr, NROW2, 4*VDIM, VDIM);
    gemm64t<0,1,0><<<dim3(4, 64), 256, 0, stream>>>(
        (const short*)sa_f1, (const short*)wsaff2T, sa_ff_b2, logits, logits, NROW2, VDIM, 4*VDIM);

    // ---- output: p = 0 slice ----
    outcopy<<<(out_size + 255)/256, 256, 0, stream>>>(logits, out);
}